// Round 8
// baseline (431.188 us; speedup 1.0000x reference)
//
#include <hip/hip_runtime.h>
#include <hip/hip_bf16.h>
#include <math.h>

#define DM   1024   // d_model
#define DI   2048   // d_inner
#define DTR  64     // dt_rank
#define DST  16     // d_state
#define NB   2      // batch
#define LL   1024   // seq len
#define MR   (NB*LL)  // 2048 rows
#define XLD  128    // xdb padded leading dim
#define KS   8      // split-K factor for x-proj

typedef __bf16 bf16x8 __attribute__((ext_vector_type(8)));
typedef float  f32x4  __attribute__((ext_vector_type(4)));

__device__ __forceinline__ float siluf(float x) { return x / (1.f + __expf(-x)); }
__device__ __forceinline__ float softplusf(float x) {
    return fmaxf(x, 0.f) + log1pf(__expf(-fabsf(x)));
}
__device__ __forceinline__ unsigned short f2bf(float f) {
    __hip_bfloat16 h = __float2bfloat16(f);
    return *reinterpret_cast<unsigned short*>(&h);
}
__device__ __forceinline__ float bf2f(__hip_bfloat16 h) { return __bfloat162float(h); }

__device__ __forceinline__ void gl2lds16(const __hip_bfloat16* g, __hip_bfloat16* l)
{
    __builtin_amdgcn_global_load_lds(
        (const __attribute__((address_space(1))) unsigned int*)g,
        (__attribute__((address_space(3))) unsigned int*)l, 16, 0, 0);
}

// ---------------- mega-prep: weight cvts + transpose + layernorm + out init ----------------
// sections by blockIdx.x:
//   [0, 10496)        cvt_all: fp32->bf16 of inW x2, proj_W, dtW x2 into warena
//   [10496, 10624)    pad96: xprojW -> bf16 padded to 128 rows, both dirs
//   [10624, 11648)    transpose: outW [DM][DI] -> [DI][DM] bf16, both dirs
//   [11648, 13696)    layernorm -> nb bf16
//   [13696, 15744)    out init: d_out = x + proj_b
__global__ __launch_bounds__(256) void prep_k(
    const float* __restrict__ s0, const float* __restrict__ s1,
    const float* __restrict__ s2, const float* __restrict__ s3,
    const float* __restrict__ s4, __hip_bfloat16* __restrict__ warena,
    const float* __restrict__ fx, const float* __restrict__ bx,
    __hip_bfloat16* __restrict__ wpb2,
    const float* __restrict__ fo, const float* __restrict__ bo,
    __hip_bfloat16* __restrict__ wot,
    const float* __restrict__ x, const float* __restrict__ lnw,
    const float* __restrict__ lnb, __hip_bfloat16* __restrict__ nb,
    const float* __restrict__ proj_b, float* __restrict__ outp)
{
    __shared__ float pshm[64 * 65];
    const int b = blockIdx.x;
    const int tid = threadIdx.x;

    if (b < 10496) {
        long idx = (long)b * 1024 + tid * 4;
        const float* src; long off;
        if      (idx <  4194304L) { src = s0; off = idx; }
        else if (idx <  8388608L) { src = s1; off = idx -  4194304L; }
        else if (idx < 10485760L) { src = s2; off = idx -  8388608L; }
        else if (idx < 10616832L) { src = s3; off = idx - 10485760L; }
        else                      { src = s4; off = idx - 10616832L; }
        float4 v = *(const float4*)(src + off);
        ushort4 o;
        o.x = f2bf(v.x); o.y = f2bf(v.y); o.z = f2bf(v.z); o.w = f2bf(v.w);
        *(ushort4*)((unsigned short*)warena + idx) = o;
    } else if (b < 10624) {
        int t = b - 10496;
        int z = t >> 6;
        const float* in = z ? bx : fx;
        int idx = ((t & 63) * 256 + tid) * 4;   // over 128*DI
        int row = idx >> 11;
        ushort4 o = make_ushort4(0, 0, 0, 0);
        if (row < 96) {
            float4 v = *(const float4*)(in + idx);
            o.x = f2bf(v.x); o.y = f2bf(v.y); o.z = f2bf(v.z); o.w = f2bf(v.w);
        }
        *(ushort4*)((unsigned short*)wpb2 + (size_t)z * 128 * DI + idx) = o;
    } else if (b < 11648) {
        int t = b - 10624;
        int z = t >> 9; t &= 511;
        const float* src = z ? bo : fo;
        int c0 = (t & 31) * 64;    // col in src (DI dim)
        int r0 = (t >> 5) * 64;    // row in src (DM dim)
        int tc = tid & 63;
        int tr = tid >> 6;
        #pragma unroll
        for (int ii = 0; ii < 16; ++ii) {
            int rl = tr + ii * 4;
            pshm[tc * 65 + rl] = src[(size_t)(r0 + rl) * DI + c0 + tc];
        }
        __syncthreads();
        __hip_bfloat16* dst = wot + (size_t)z * DI * DM;
        #pragma unroll
        for (int ii = 0; ii < 16; ++ii) {
            int cl = tr + ii * 4;
            dst[(size_t)(c0 + cl) * DM + r0 + tc] = __float2bfloat16(pshm[cl * 65 + tc]);
        }
    } else if (b < 13696) {
        int row = b - 11648;
        const float* xr = x + (size_t)row * DM;
        float4 v = *(const float4*)(xr + tid * 4);
        float s = v.x + v.y + v.z + v.w;
        float q = v.x*v.x + v.y*v.y + v.z*v.z + v.w*v.w;
        #pragma unroll
        for (int off = 32; off > 0; off >>= 1) {
            s += __shfl_xor(s, off, 64);
            q += __shfl_xor(q, off, 64);
        }
        int wv = tid >> 6;
        if ((tid & 63) == 0) { pshm[wv] = s; pshm[8 + wv] = q; }
        __syncthreads();
        s = pshm[0] + pshm[1] + pshm[2] + pshm[3];
        q = pshm[8] + pshm[9] + pshm[10] + pshm[11];
        float mu  = s * (1.f / DM);
        float var = q * (1.f / DM) - mu * mu;
        float rstd = rsqrtf(var + 1e-5f);
        float4 wv4 = *(const float4*)(lnw + tid * 4);
        float4 bv4 = *(const float4*)(lnb + tid * 4);
        ushort4 o;
        o.x = f2bf((v.x - mu) * rstd * wv4.x + bv4.x);
        o.y = f2bf((v.y - mu) * rstd * wv4.y + bv4.y);
        o.z = f2bf((v.z - mu) * rstd * wv4.z + bv4.z);
        o.w = f2bf((v.w - mu) * rstd * wv4.w + bv4.w);
        *(ushort4*)((unsigned short*)nb + (size_t)row * DM + tid * 4) = o;
    } else {
        size_t idx = ((size_t)(b - 13696) * 256 + tid) * 4;   // over MR*DM
        float4 xv = *(const float4*)(x + idx);
        float4 pb = *(const float4*)(proj_b + (idx & (DM - 1)));
        float4 o;
        o.x = xv.x + pb.x; o.y = xv.y + pb.y; o.z = xv.z + pb.z; o.w = xv.w + pb.w;
        *(float4*)(outp + idx) = o;
    }
}

// ---------------- bf16 MFMA GEMM with global_load_lds staging ----------------
// C[m,n] = sum_k A[m,k]*B[n,k]. 128x128 tile, BK=64, 256 thr (4 waves x 64x64).
// XOR-swizzled LDS; zero bank conflicts. z-grouped via element offsets.
// EPI: 1 = bf16 store (LDS-staged, vectorized), 3 = softplus(v+bias_z[n]) bf16
// (LDS-staged), 4 = fp32 atomicAdd into C (split-K accumulate).
template<int EPI>
__global__ __launch_bounds__(256) void gemm_gl(
    const __hip_bfloat16* __restrict__ A, int lda, size_t aofs,
    const __hip_bfloat16* __restrict__ B, int ldb, size_t bofs,
    void* __restrict__ Cp, int ldc, size_t cofs, int K,
    const float* __restrict__ bias0, const float* __restrict__ bias1)
{
    __shared__ __hip_bfloat16 smem[2 * 128 * 64];
    __hip_bfloat16* As = smem;
    __hip_bfloat16* Bs = smem + 128 * 64;
    const int tid  = threadIdx.x;
    const int z    = blockIdx.z;
    const int bm   = blockIdx.y * 128;
    const int bn   = blockIdx.x * 128;
    const __hip_bfloat16* Az = A + (size_t)z * aofs;
    const __hip_bfloat16* Bz = B + (size_t)z * bofs;
    const int wv   = tid >> 6;
    const int lane = tid & 63;
    const int wr   = (wv >> 1) * 64;
    const int wc   = (wv & 1) * 64;
    const int srow = wv * 32 + (lane >> 3);
    const int cg   = ((lane & 7) ^ (lane >> 3)) * 8;
    const int fr   = lane & 15;
    const int quad = lane >> 4;
    const int pc0  = (quad ^ (fr & 7)) * 8;
    const int pc1  = ((4 + quad) ^ (fr & 7)) * 8;

    f32x4 acc[4][4] = {};

    for (int k0 = 0; k0 < K; k0 += 64) {
        __syncthreads();
        #pragma unroll
        for (int i = 0; i < 4; ++i) {
            int r = srow + i * 8;
            gl2lds16(Az + (size_t)(bm + r) * lda + k0 + cg, As + wv * 2048 + i * 512);
            gl2lds16(Bz + (size_t)(bn + r) * ldb + k0 + cg, Bs + wv * 2048 + i * 512);
        }
        __syncthreads();
        #pragma unroll
        for (int kk = 0; kk < 2; ++kk) {
            const int pc = kk ? pc1 : pc0;
            bf16x8 af[4], bf_[4];
            #pragma unroll
            for (int i = 0; i < 4; ++i) {
                af[i]  = *(const bf16x8*)(As + (wr + i * 16 + fr) * 64 + pc);
                bf_[i] = *(const bf16x8*)(Bs + (wc + i * 16 + fr) * 64 + pc);
            }
            #pragma unroll
            for (int i = 0; i < 4; ++i)
                #pragma unroll
                for (int j = 0; j < 4; ++j)
                    acc[i][j] = __builtin_amdgcn_mfma_f32_16x16x32_bf16(
                        af[i], bf_[j], acc[i][j], 0, 0, 0);
        }
    }

    if (EPI == 4) {
        // fp32 atomic accumulate (split-K): direct scalar atomics
        const int er = quad * 4;
        #pragma unroll
        for (int i = 0; i < 4; ++i)
            #pragma unroll
            for (int j = 0; j < 4; ++j) {
                int row = bm + wr + i * 16 + er;
                int col = bn + wc + j * 16 + fr;
                #pragma unroll
                for (int r = 0; r < 4; ++r)
                    atomicAdd((float*)Cp + (size_t)(row + r) * ldc + col, acc[i][j][r]);
            }
        return;
    }

    // bf16 epilogue via LDS restage (32 rows x 132 fp32) -> vectorized stores
    const float* bias = (EPI == 3) ? (z ? bias1 : bias0) : nullptr;
    float* eps = (float*)smem;
    const int half = wv >> 1;
    const int lrow = tid >> 3;          // 0..31
    const int cseg = (tid & 7) * 16;    // 0..112
    const int gr_  = bm + (lrow >> 4) * 64 + (lrow & 15);
    #pragma unroll
    for (int i = 0; i < 4; ++i) {
        __syncthreads();
        #pragma unroll
        for (int j = 0; j < 4; ++j)
            #pragma unroll
            for (int r = 0; r < 4; ++r)
                eps[(half * 16 + quad * 4 + r) * 132 + wc + j * 16 + fr] = acc[i][j][r];
        __syncthreads();
        float vals[16];
        *(float4*)(vals +  0) = *(const float4*)(eps + lrow * 132 + cseg +  0);
        *(float4*)(vals +  4) = *(const float4*)(eps + lrow * 132 + cseg +  4);
        *(float4*)(vals +  8) = *(const float4*)(eps + lrow * 132 + cseg +  8);
        *(float4*)(vals + 12) = *(const float4*)(eps + lrow * 132 + cseg + 12);
        int gr = gr_ + i * 16;
        int gc = bn + cseg;
        unsigned short os[16];
        #pragma unroll
        for (int c = 0; c < 16; ++c) {
            float t = vals[c];
            if (EPI == 3) t = softplusf(t + bias[gc + c]);
            os[c] = f2bf(t);
        }
        unsigned short* dst = (unsigned short*)Cp + (size_t)z * cofs +
                              (size_t)gr * ldc + gc;
        *(ushort4*)(dst +  0) = *(ushort4*)(os +  0);
        *(ushort4*)(dst +  4) = *(ushort4*)(os +  4);
        *(ushort4*)(dst +  8) = *(ushort4*)(os +  8);
        *(ushort4*)(dst + 12) = *(ushort4*)(os + 12);
    }
}

// ---------------- x-proj split-K partials, grouped over dir ----------------
__global__ __launch_bounds__(256) void xproj_part_k(
    const __hip_bfloat16* __restrict__ A,
    const __hip_bfloat16* __restrict__ B,
    float* __restrict__ part)
{
    __shared__ __hip_bfloat16 smem[2 * 128 * 64];
    __hip_bfloat16* As = smem;
    __hip_bfloat16* Bs = smem + 128 * 64;
    const int tid  = threadIdx.x;
    const int ks   = blockIdx.x;
    const int bm   = blockIdx.y * 128;
    const int z    = blockIdx.z;
    const __hip_bfloat16* Az = A + (size_t)z * MR * DI;
    const __hip_bfloat16* Bz = B + (size_t)z * 128 * DI;
    const int kb   = ks * (DI / KS);
    const int wv   = tid >> 6;
    const int lane = tid & 63;
    const int wr   = (wv >> 1) * 64;
    const int wc   = (wv & 1) * 64;
    const int srow = wv * 32 + (lane >> 3);
    const int cg   = ((lane & 7) ^ (lane >> 3)) * 8;
    const int fr   = lane & 15;
    const int quad = lane >> 4;
    const int pc0  = (quad ^ (fr & 7)) * 8;
    const int pc1  = ((4 + quad) ^ (fr & 7)) * 8;

    f32x4 acc[4][4] = {};

    #pragma unroll
    for (int k0 = 0; k0 < DI / KS; k0 += 64) {
        __syncthreads();
        #pragma unroll
        for (int i = 0; i < 4; ++i) {
            int r = srow + i * 8;
            gl2lds16(Az + (size_t)(bm + r) * DI + kb + k0 + cg, As + wv * 2048 + i * 512);
            gl2lds16(Bz + (size_t)r * DI + kb + k0 + cg,        Bs + wv * 2048 + i * 512);
        }
        __syncthreads();
        #pragma unroll
        for (int kk = 0; kk < 2; ++kk) {
            const int pc = kk ? pc1 : pc0;
            bf16x8 af[4], bf_[4];
            #pragma unroll
            for (int i = 0; i < 4; ++i) {
                af[i]  = *(const bf16x8*)(As + (wr + i * 16 + fr) * 64 + pc);
                bf_[i] = *(const bf16x8*)(Bs + (wc + i * 16 + fr) * 64 + pc);
            }
            #pragma unroll
            for (int i = 0; i < 4; ++i)
                #pragma unroll
                for (int j = 0; j < 4; ++j)
                    acc[i][j] = __builtin_amdgcn_mfma_f32_16x16x32_bf16(
                        af[i], bf_[j], acc[i][j], 0, 0, 0);
        }
    }

    float* dst = part + ((size_t)z * KS + ks) * MR * XLD;
    const int er = quad * 4;
    #pragma unroll
    for (int i = 0; i < 4; ++i)
        #pragma unroll
        for (int j = 0; j < 4; ++j) {
            int row = bm + wr + i * 16 + er;
            int col = wc + j * 16 + fr;
            #pragma unroll
            for (int r = 0; r < 4; ++r)
                dst[(size_t)(row + r) * XLD + col] = acc[i][j][r];
        }
}

// ---------------- reduce x-proj partials -> xdb2 fp32 + dt-cols bf16 ----------------
__global__ __launch_bounds__(256) void xproj_reduce_k(
    const float* __restrict__ part, float* __restrict__ xdb,
    __hip_bfloat16* __restrict__ xdbt)
{
    int z = blockIdx.y;
    size_t idx = ((size_t)blockIdx.x * 256 + threadIdx.x) * 4;   // over MR*XLD
    const float* p = part + (size_t)z * KS * MR * XLD;
    float4 s = make_float4(0.f, 0.f, 0.f, 0.f);
    #pragma unroll
    for (int ks = 0; ks < KS; ++ks) {
        float4 v = *(const float4*)(p + (size_t)ks * MR * XLD + idx);
        s.x += v.x; s.y += v.y; s.z += v.z; s.w += v.w;
    }
    *(float4*)(xdb + (size_t)z * MR * XLD + idx) = s;
    int c = (int)(idx & (XLD - 1));
    if (c < 64) {
        size_t m = idx >> 7;
        ushort4 o;
        o.x = f2bf(s.x); o.y = f2bf(s.y); o.z = f2bf(s.z); o.w = f2bf(s.w);
        *(ushort4*)((unsigned short*)xdbt + (size_t)z * MR * 64 + m * 64 + c) = o;
    }
}

// ---------------- Depthwise conv (width 4) + SiLU, both dirs ----------------
__global__ __launch_bounds__(256) void conv_silu_k(
    const __hip_bfloat16* __restrict__ xz2,
    const float* __restrict__ fW, const float* __restrict__ fb,
    const float* __restrict__ bW, const float* __restrict__ bb_,
    __hip_bfloat16* __restrict__ xsb2)
{
    int dirv = blockIdx.y;
    int idx = blockIdx.x * 256 + threadIdx.x;   // over MR*DI
    int d = idx & (DI - 1);
    int m = idx >> 11;
    int t = m & (LL - 1);
    int bb = m >> 10;
    const float* w  = (dirv ? bW : fW) + d * 4;
    const __hip_bfloat16* xz = xz2 + (size_t)dirv * MR * 2 * DI;
    float acc = (dirv ? bb_ : fb)[d];
    if (dirv == 0) {
        #pragma unroll
        for (int k = 0; k < 4; ++k) {
            int tt = t - 3 + k;
            if (tt >= 0)
                acc = fmaf(w[k], bf2f(xz[(size_t)(bb * LL + tt) * (2 * DI) + d]), acc);
        }
    } else {
        #pragma unroll
        for (int k = 0; k < 4; ++k) {
            int tt = t + 3 - k;
            if (tt < LL)
                acc = fmaf(w[k], bf2f(xz[(size_t)(bb * LL + tt) * (2 * DI) + d]), acc);
        }
    }
    xsb2[(size_t)dirv * MR * DI + (size_t)m * DI + d] = __float2bfloat16(siluf(acc));
}

// ---------------- Chunked selective scan, both dirs ----------------
// A_log structurally log(tile(arange(1..17))) -> dA_s = r^(s+1), r = exp(-dt),
// guarded per-thread; exact path otherwise.
__global__ __launch_bounds__(256) void scan1_k(
    const __hip_bfloat16* __restrict__ dtf2, const __hip_bfloat16* __restrict__ xsb2,
    const float* __restrict__ xdb2,
    const float* __restrict__ fA, const float* __restrict__ bA,
    float* __restrict__ hend, float* __restrict__ aprod, int G, int Cn)
{
    int d  = blockIdx.x * 256 + threadIdx.x;
    int bb = blockIdx.y;
    int zz = blockIdx.z;
    int dirv = (zz >= G) ? 1 : 0;
    int g = zz - (dirv ? G : 0);
    const float* A_log = dirv ? bA : fA;
    const __hip_bfloat16* dtf = dtf2 + (size_t)dirv * MR * DI;
    const __hip_bfloat16* xs = xsb2 + (size_t)dirv * MR * DI;
    const float* xdb = xdb2 + (size_t)dirv * MR * XLD;
    size_t hoff = (size_t)dirv * G * (NB * DI * DST);

    float Ad[DST], h[DST], ap[DST];
    bool pw = true;
    #pragma unroll
    for (int s = 0; s < DST; ++s) {
        Ad[s] = -__expf(A_log[d * DST + s]);
        pw = pw && (fabsf(Ad[s] + (float)(s + 1)) < 1e-3f * (s + 1));
        h[s] = 0.f; ap[s] = 1.f;
    }
    int i0 = g * Cn;
    for (int i = 0; i < Cn; ++i) {
        int ii = i0 + i;
        int t = dirv ? (LL - 1 - ii) : ii;
        size_t m = (size_t)bb * LL + t;
        float dtv = bf2f(dtf[m * DI + d]);
        float xv  = bf2f(xs[m * DI + d]);
        const float* bc = xdb + m * XLD;
        float dtx = dtv * xv;
        float dAv[DST];
        if (pw) {
            float r = __expf(-dtv);
            float a = r;
            #pragma unroll
            for (int s = 0; s < DST; ++s) { dAv[s] = a; a *= r; }
        } else {
            #pragma unroll
            for (int s = 0; s < DST; ++s) dAv[s] = __expf(dtv * Ad[s]);
        }
        #pragma unroll
        for (int s = 0; s < DST; ++s) {
            h[s] = fmaf(h[s], dAv[s], dtx * bc[64 + s]);
            ap[s] *= dAv[s];
        }
    }
    size_t base = hoff + ((size_t)(g * NB + bb) * DI + d) * DST;
    #pragma unroll
    for (int s = 0; s < DST; s += 4) {
        *(float4*)(hend  + base + s) = make_float4(h[s], h[s+1], h[s+2], h[s+3]);
        *(float4*)(aprod + base + s) = make_float4(ap[s], ap[s+1], ap[s+2], ap[s+3]);
    }
}

__global__ __launch_bounds__(256) void scan2_k(
    float* __restrict__ hend, const float* __restrict__ aprod, int G)
{
    int dirv = blockIdx.y;
    int idx = blockIdx.x * 256 + threadIdx.x;   // over NB*DI*DST
    const int slab = NB * DI * DST;
    size_t hoff = (size_t)dirv * G * slab;
    float carry = 0.f;
    for (int g = 0; g < G; ++g) {
        size_t off = hoff + (size_t)g * slab + idx;
        float a = aprod[off];
        float e = hend[off];
        hend[off] = carry;
        carry = fmaf(a, carry, e);
    }
}

__global__ __launch_bounds__(256) void scan3_k(
    const __hip_bfloat16* __restrict__ dtf2, const __hip_bfloat16* __restrict__ xsb2,
    const float* __restrict__ xdb2, const __hip_bfloat16* __restrict__ xz2,
    const float* __restrict__ fA, const float* __restrict__ bA,
    const float* __restrict__ fD, const float* __restrict__ bD,
    const float* __restrict__ hin, __hip_bfloat16* __restrict__ ycat, int G, int Cn)
{
    int d  = blockIdx.x * 256 + threadIdx.x;
    int bb = blockIdx.y;
    int zz = blockIdx.z;
    int dirv = (zz >= G) ? 1 : 0;
    int g = zz - (dirv ? G : 0);
    const float* A_log = dirv ? bA : fA;
    const float* Dskip = dirv ? bD : fD;
    const __hip_bfloat16* dtf = dtf2 + (size_t)dirv * MR * DI;
    const __hip_bfloat16* xs = xsb2 + (size_t)dirv * MR * DI;
    const float* xdb = xdb2 + (size_t)dirv * MR * XLD;
    const __hip_bfloat16* xz = xz2 + (size_t)dirv * MR * 2 * DI;
    size_t hoff = (size_t)dirv * G * (NB * DI * DST);

    float Ad[DST], h[DST];
    bool pw = true;
    size_t base = hoff + ((size_t)(g * NB + bb) * DI + d) * DST;
    #pragma unroll
    for (int s = 0; s < DST; ++s) {
        Ad[s] = -__expf(A_log[d * DST + s]);
        pw = pw && (fabsf(Ad[s] + (float)(s + 1)) < 1e-3f * (s + 1));
        h[s] = hin[base + s];
    }
    float Dsk = Dskip[d];
    int i0 = g * Cn;
    for (int i = 0; i < Cn; ++i) {
        int ii = i0 + i;
        int t = dirv ? (LL - 1 - ii) : ii;
        size_t m = (size_t)bb * LL + t;
        float dtv = bf2f(dtf[m * DI + d]);
        float xv  = bf2f(xs[m * DI + d]);
        const float* bc = xdb + m * XLD;
        float dtx = dtv * xv;
        float dAv[DST];
        if (pw) {
            float r = __expf(-dtv);
            float a = r;
            #pragma unroll
            for (int s = 0; s < DST; ++s) { dAv[s] = a; a *= r; }
        } else {
            #pragma unroll
            for (int s = 0; s < DST; ++s) dAv[s] = __expf(dtv * Ad[s]);
        }
        float yv = 0.f;
        #pragma unroll
        for (int s = 0; s < DST; ++s) {
            h[s] = fmaf(h[s], dAv[s], dtx * bc[64 + s]);
            yv = fmaf(h[s], bc[80 + s], yv);
        }
        float zv = bf2f(xz[m * (2 * DI) + DI + d]);
        ycat[m * (2 * DI) + (size_t)dirv * DI + d] =
            __float2bfloat16((yv + xv * Dsk) * siluf(zv));
    }
}

// fallback monolithic scan (both dirs) if ws too small for chunk bufs
__global__ __launch_bounds__(256) void scan_mono_k(
    const __hip_bfloat16* __restrict__ dtf2, const __hip_bfloat16* __restrict__ xsb2,
    const float* __restrict__ xdb2, const __hip_bfloat16* __restrict__ xz2,
    const float* __restrict__ fA, const float* __restrict__ bA,
    const float* __restrict__ fD, const float* __restrict__ bD,
    __hip_bfloat16* __restrict__ ycat)
{
    int d  = blockIdx.x * 256 + threadIdx.x;
    int bb = blockIdx.y;
    int dirv = blockIdx.z;
    const float* A_log = dirv ? bA : fA;
    const float* Dskip = dirv ? bD : fD;
    const __hip_bfloat16* dtf = dtf2 + (size_t)dirv * MR * DI;
    const __hip_bfloat16* xs = xsb2 + (size_t)dirv * MR * DI;
    const float* xdb = xdb2 + (size_t)dirv * MR * XLD;
    const __hip_bfloat16* xz = xz2 + (size_t)dirv * MR * 2 * DI;
    float Ad[DST], h[DST];
    #pragma unroll
    for (int s = 0; s < DST; ++s) { Ad[s] = -__expf(A_log[d * DST + s]); h[s] = 0.f; }
    float Dsk = Dskip[d];
    for (int i = 0; i < LL; ++i) {
        int t = dirv ? (LL - 1 - i) : i;
        size_t m = (size_t)bb * LL + t;
        float dtv = bf2f(dtf[m * DI + d]);
        float xv  = bf2f(xs[m * DI + d]);
        const float* bc = xdb + m * XLD;
        float dtx = dtv * xv;
        float yv = 0.f;
        #pragma unroll
        for (int s = 0; s < DST; ++s) {
            float dA = __expf(dtv * Ad[s]);
            h[s] = fmaf(h[s], dA, dtx * bc[64 + s]);
            yv = fmaf(h[s], bc[80 + s], yv);
        }
        float zv = bf2f(xz[m * (2 * DI) + DI + d]);
        ycat[m * (2 * DI) + (size_t)dirv * DI + d] =
            __float2bfloat16((yv + xv * Dsk) * siluf(zv));
    }
}

// ---------------- Launch ----------------
extern "C" void kernel_launch(void* const* d_in, const int* in_sizes, int n_in,
                              void* d_out, int out_size, void* d_ws, size_t ws_size,
                              hipStream_t stream)
{
    const float* x      = (const float*)d_in[0];
    const float* ln_w   = (const float*)d_in[1];
    const float* ln_b   = (const float*)d_in[2];
    const float* f_inW    = (const float*)d_in[3];
    const float* f_convW  = (const float*)d_in[4];
    const float* f_convb  = (const float*)d_in[5];
    const float* f_xprojW = (const float*)d_in[6];
    const float* f_dtW    = (const float*)d_in[7];
    const float* f_dtb    = (const float*)d_in[8];
    const float* f_A_log  = (const float*)d_in[9];
    const float* f_Dskip  = (const float*)d_in[10];
    const float* f_outW   = (const float*)d_in[11];
    const float* b_inW    = (const float*)d_in[12];
    const float* b_convW  = (const float*)d_in[13];
    const float* b_convb  = (const float*)d_in[14];
    const float* b_xprojW = (const float*)d_in[15];
    const float* b_dtW    = (const float*)d_in[16];
    const float* b_dtb    = (const float*)d_in[17];
    const float* b_A_log  = (const float*)d_in[18];
    const float* b_Dskip  = (const float*)d_in[19];
    const float* b_outW   = (const float*)d_in[20];
    const float* proj_W = (const float*)d_in[21];
    const float* proj_b = (const float*)d_in[22];

    float* ws = (float*)d_ws;
    size_t o = 0;
    // xz2 region: wot [2][DI][DM] bf16 during prep (dead after Wcat GEMM),
    // then xz2 bf16 [2][MR][2DI].
    __hip_bfloat16* xz2  = (__hip_bfloat16*)(ws + o);
    __hip_bfloat16* wot  = xz2;
    o += (size_t)2 * MR * 2 * DI / 2;
    __hip_bfloat16* xsb2 = (__hip_bfloat16*)(ws + o); o += (size_t)2 * MR * DI / 2;
    // ycat region: x-proj split-K fp32 partials first, then ycat bf16 [MR][2DI].
    __hip_bfloat16* ycat = (__hip_bfloat16*)(ws + o);
    float* xpart = ws + o;
    o += (size_t)MR * 2 * DI / 2;
    float* xdb2 = ws + o; o += (size_t)2 * MR * XLD;
    __hip_bfloat16* xdbt = (__hip_bfloat16*)(ws + o); o += (size_t)2 * MR * 64 / 2;
    __hip_bfloat16* dtfb = (__hip_bfloat16*)(ws + o); o += (size_t)2 * MR * DI / 2;
    __hip_bfloat16* nb = (__hip_bfloat16*)(ws + o); o += (size_t)MR * DM / 2;
    __hip_bfloat16* warena = (__hip_bfloat16*)(ws + o); o += 15466496 / 2;
    float* hbuf = ws + o;
    size_t base_floats = o;

    __hip_bfloat16* wbi  = warena;               // [2][2DI][DM]    8,388,608
    __hip_bfloat16* pwb  = warena +  8388608;    // [DM][2DM]       2,097,152
    __hip_bfloat16* wdt  = warena + 10485760;    // [2][DI][64]       262,144
    __hip_bfloat16* wpb2 = warena + 10747904;    // [2][128][DI]      524,288
    __hip_bfloat16* wcat = warena + 11272192;    // [DM][2DI]       4,194,304

    const size_t slab = (size_t)NB * DI * DST;   // 65536
    int G = 32;
    while (G > 4 && (base_floats + 4ull * G * slab) * 4 > ws_size) G >>= 1;
    int useChunks = ((base_floats + 4ull * G * slab) * 4 <= ws_size);
    float* hend  = hbuf;
    float* aprod = hbuf + 2ull * G * slab;
    int Cn = useChunks ? LL / G : LL;

    // 1: mega-prep (weight cvts + transpose + layernorm + out init)
    prep_k<<<15744, 256, 0, stream>>>(
        f_inW, b_inW, proj_W, f_dtW, b_dtW, warena,
        f_xprojW, b_xprojW, wpb2,
        f_outW, b_outW, wot,
        x, ln_w, ln_b, nb,
        proj_b, (float*)d_out);

    // 2: Wcat[e, z*DI+d] = sum_{e'} proj_W[e, z*DM+e'] * outW_z[e', d]
    gemm_gl<1><<<dim3(DI / 128, DM / 128, 2), 256, 0, stream>>>(
        pwb, 2 * DM, (size_t)DM, wot, DM, (size_t)DI * DM,
        wcat, 2 * DI, (size_t)DI, DM, nullptr, nullptr);

    // 3: in-proj both dirs (overwrites wot)
    gemm_gl<1><<<dim3((2 * DI) / 128, MR / 128, 2), 256, 0, stream>>>(
        nb, DM, 0, wbi, DM, (size_t)2 * DI * DM,
        xz2, 2 * DI, (size_t)MR * 2 * DI, DM, nullptr, nullptr);

    // 4: conv + silu both dirs -> xsb2
    conv_silu_k<<<dim3((MR * DI) / 256, 2), 256, 0, stream>>>(
        xz2, f_convW, f_convb, b_convW, b_convb, xsb2);

    // 5-6: x-proj split-K + reduce
    xproj_part_k<<<dim3(KS, MR / 128, 2), 256, 0, stream>>>(xsb2, wpb2, xpart);
    xproj_reduce_k<<<dim3((MR * XLD) / 1024, 2), 256, 0, stream>>>(xpart, xdb2, xdbt);

    // 7: dt-proj both dirs: dtfb = softplus(xdbt @ dtW^T + dtb) (bf16)
    gemm_gl<3><<<dim3(DI / 128, MR / 128, 2), 256, 0, stream>>>(
        xdbt, 64, (size_t)MR * 64, wdt, 64, (size_t)DI * 64,
        dtfb, DI, (size_t)MR * DI, 64, f_dtb, b_dtb);

    // 8-10: selective scan both dirs -> ycat [MR][2*DI]
    if (useChunks) {
        scan1_k<<<dim3(DI / 256, NB, 2 * G), 256, 0, stream>>>(
            dtfb, xsb2, xdb2, f_A_log, b_A_log, hend, aprod, G, Cn);
        scan2_k<<<dim3((NB * DI * DST) / 256, 2), 256, 0, stream>>>(hend, aprod, G);
        scan3_k<<<dim3(DI / 256, NB, 2 * G), 256, 0, stream>>>(
            dtfb, xsb2, xdb2, xz2, f_A_log, b_A_log, f_Dskip, b_Dskip,
            hend, ycat, G, Cn);
    } else {
        scan_mono_k<<<dim3(DI / 256, NB, 2), 256, 0, stream>>>(
            dtfb, xsb2, xdb2, xz2, f_A_log, b_A_log, f_Dskip, b_Dskip, ycat);
    }

    // 11: final split-K GEMM with fp32 atomic accumulate into pre-initialized d_out
    gemm_gl<4><<<dim3(DM / 128, MR / 128, 4), 256, 0, stream>>>(
        ycat, 2 * DI, 1024, wcat, 2 * DI, 1024,
        (float*)d_out, DM, 0, 1024, nullptr, nullptr);
}

// Round 9
// 422.645 us; speedup vs baseline: 1.0202x; 1.0202x over previous
//
#include <hip/hip_runtime.h>
#include <hip/hip_bf16.h>
#include <math.h>

#define DM   1024   // d_model
#define DI   2048   // d_inner
#define DTR  64     // dt_rank
#define DST  16     // d_state
#define NB   2      // batch
#define LL   1024   // seq len
#define MR   (NB*LL)  // 2048 rows
#define XLD  128    // xdb padded leading dim
#define KS   8      // split-K factor for x-proj

typedef __bf16 bf16x8 __attribute__((ext_vector_type(8)));
typedef float  f32x4  __attribute__((ext_vector_type(4)));

__device__ __forceinline__ float siluf(float x) { return x / (1.f + __expf(-x)); }
__device__ __forceinline__ float softplusf(float x) {
    return fmaxf(x, 0.f) + log1pf(__expf(-fabsf(x)));
}
__device__ __forceinline__ unsigned short f2bf(float f) {
    __hip_bfloat16 h = __float2bfloat16(f);
    return *reinterpret_cast<unsigned short*>(&h);
}
__device__ __forceinline__ float bf2f(__hip_bfloat16 h) { return __bfloat162float(h); }

__device__ __forceinline__ void gl2lds16(const __hip_bfloat16* g, __hip_bfloat16* l)
{
    __builtin_amdgcn_global_load_lds(
        (const __attribute__((address_space(1))) unsigned int*)g,
        (__attribute__((address_space(3))) unsigned int*)l, 16, 0, 0);
}

// ---------------- mega-prep: weight cvts + transpose + layernorm ----------------
// sections by blockIdx.x:
//   [0, 10496)        cvt_all: fp32->bf16 of inW x2, proj_W, dtW x2 into warena
//   [10496, 10624)    pad96: xprojW -> bf16 padded to 128 rows, both dirs
//   [10624, 11648)    transpose: outW [DM][DI] -> [DI][DM] bf16, both dirs
//   [11648, 13696)    layernorm -> nb bf16
__global__ __launch_bounds__(256) void prep_k(
    const float* __restrict__ s0, const float* __restrict__ s1,
    const float* __restrict__ s2, const float* __restrict__ s3,
    const float* __restrict__ s4, __hip_bfloat16* __restrict__ warena,
    const float* __restrict__ fx, const float* __restrict__ bx,
    __hip_bfloat16* __restrict__ wpb2,
    const float* __restrict__ fo, const float* __restrict__ bo,
    __hip_bfloat16* __restrict__ wot,
    const float* __restrict__ x, const float* __restrict__ lnw,
    const float* __restrict__ lnb, __hip_bfloat16* __restrict__ nb)
{
    __shared__ float pshm[64 * 65];
    const int b = blockIdx.x;
    const int tid = threadIdx.x;

    if (b < 10496) {
        long idx = (long)b * 1024 + tid * 4;
        const float* src; long off;
        if      (idx <  4194304L) { src = s0; off = idx; }
        else if (idx <  8388608L) { src = s1; off = idx -  4194304L; }
        else if (idx < 10485760L) { src = s2; off = idx -  8388608L; }
        else if (idx < 10616832L) { src = s3; off = idx - 10485760L; }
        else                      { src = s4; off = idx - 10616832L; }
        float4 v = *(const float4*)(src + off);
        ushort4 o;
        o.x = f2bf(v.x); o.y = f2bf(v.y); o.z = f2bf(v.z); o.w = f2bf(v.w);
        *(ushort4*)((unsigned short*)warena + idx) = o;
    } else if (b < 10624) {
        int t = b - 10496;
        int z = t >> 6;
        const float* in = z ? bx : fx;
        int idx = ((t & 63) * 256 + tid) * 4;   // over 128*DI
        int row = idx >> 11;
        ushort4 o = make_ushort4(0, 0, 0, 0);
        if (row < 96) {
            float4 v = *(const float4*)(in + idx);
            o.x = f2bf(v.x); o.y = f2bf(v.y); o.z = f2bf(v.z); o.w = f2bf(v.w);
        }
        *(ushort4*)((unsigned short*)wpb2 + (size_t)z * 128 * DI + idx) = o;
    } else if (b < 11648) {
        int t = b - 10624;
        int z = t >> 9; t &= 511;
        const float* src = z ? bo : fo;
        int c0 = (t & 31) * 64;    // col in src (DI dim)
        int r0 = (t >> 5) * 64;    // row in src (DM dim)
        int tc = tid & 63;
        int tr = tid >> 6;
        #pragma unroll
        for (int ii = 0; ii < 16; ++ii) {
            int rl = tr + ii * 4;
            pshm[tc * 65 + rl] = src[(size_t)(r0 + rl) * DI + c0 + tc];
        }
        __syncthreads();
        __hip_bfloat16* dst = wot + (size_t)z * DI * DM;
        #pragma unroll
        for (int ii = 0; ii < 16; ++ii) {
            int cl = tr + ii * 4;
            dst[(size_t)(c0 + cl) * DM + r0 + tc] = __float2bfloat16(pshm[cl * 65 + tc]);
        }
    } else {
        int row = b - 11648;
        const float* xr = x + (size_t)row * DM;
        float4 v = *(const float4*)(xr + tid * 4);
        float s = v.x + v.y + v.z + v.w;
        float q = v.x*v.x + v.y*v.y + v.z*v.z + v.w*v.w;
        #pragma unroll
        for (int off = 32; off > 0; off >>= 1) {
            s += __shfl_xor(s, off, 64);
            q += __shfl_xor(q, off, 64);
        }
        int wv = tid >> 6;
        if ((tid & 63) == 0) { pshm[wv] = s; pshm[8 + wv] = q; }
        __syncthreads();
        s = pshm[0] + pshm[1] + pshm[2] + pshm[3];
        q = pshm[8] + pshm[9] + pshm[10] + pshm[11];
        float mu  = s * (1.f / DM);
        float var = q * (1.f / DM) - mu * mu;
        float rstd = rsqrtf(var + 1e-5f);
        float4 wv4 = *(const float4*)(lnw + tid * 4);
        float4 bv4 = *(const float4*)(lnb + tid * 4);
        ushort4 o;
        o.x = f2bf((v.x - mu) * rstd * wv4.x + bv4.x);
        o.y = f2bf((v.y - mu) * rstd * wv4.y + bv4.y);
        o.z = f2bf((v.z - mu) * rstd * wv4.z + bv4.z);
        o.w = f2bf((v.w - mu) * rstd * wv4.w + bv4.w);
        *(ushort4*)((unsigned short*)nb + (size_t)row * DM + tid * 4) = o;
    }
}

// ---------------- bf16 MFMA GEMM with global_load_lds staging ----------------
// C[m,n] = sum_k A[m,k]*B[n,k]. 128x128 tile, BK=64, 256 thr (4 waves x 64x64).
// XOR-swizzled LDS; zero bank conflicts. z-grouped via element offsets.
// All epilogues LDS-restaged for full-line vectorized stores.
// EPI: 0 = fp32 store, 1 = bf16 store, 3 = softplus(v+bias_z[n]) bf16 store.
template<int EPI>
__global__ __launch_bounds__(256) void gemm_gl(
    const __hip_bfloat16* __restrict__ A, int lda, size_t aofs,
    const __hip_bfloat16* __restrict__ B, int ldb, size_t bofs,
    void* __restrict__ Cp, int ldc, size_t cofs, int K,
    const float* __restrict__ bias0, const float* __restrict__ bias1)
{
    __shared__ __hip_bfloat16 smem[2 * 128 * 64];
    __hip_bfloat16* As = smem;
    __hip_bfloat16* Bs = smem + 128 * 64;
    const int tid  = threadIdx.x;
    const int z    = blockIdx.z;
    const int bm   = blockIdx.y * 128;
    const int bn   = blockIdx.x * 128;
    const __hip_bfloat16* Az = A + (size_t)z * aofs;
    const __hip_bfloat16* Bz = B + (size_t)z * bofs;
    const int wv   = tid >> 6;
    const int lane = tid & 63;
    const int wr   = (wv >> 1) * 64;
    const int wc   = (wv & 1) * 64;
    const int srow = wv * 32 + (lane >> 3);
    const int cg   = ((lane & 7) ^ (lane >> 3)) * 8;
    const int fr   = lane & 15;
    const int quad = lane >> 4;
    const int pc0  = (quad ^ (fr & 7)) * 8;
    const int pc1  = ((4 + quad) ^ (fr & 7)) * 8;

    f32x4 acc[4][4] = {};

    for (int k0 = 0; k0 < K; k0 += 64) {
        __syncthreads();
        #pragma unroll
        for (int i = 0; i < 4; ++i) {
            int r = srow + i * 8;
            gl2lds16(Az + (size_t)(bm + r) * lda + k0 + cg, As + wv * 2048 + i * 512);
            gl2lds16(Bz + (size_t)(bn + r) * ldb + k0 + cg, Bs + wv * 2048 + i * 512);
        }
        __syncthreads();
        #pragma unroll
        for (int kk = 0; kk < 2; ++kk) {
            const int pc = kk ? pc1 : pc0;
            bf16x8 af[4], bf_[4];
            #pragma unroll
            for (int i = 0; i < 4; ++i) {
                af[i]  = *(const bf16x8*)(As + (wr + i * 16 + fr) * 64 + pc);
                bf_[i] = *(const bf16x8*)(Bs + (wc + i * 16 + fr) * 64 + pc);
            }
            #pragma unroll
            for (int i = 0; i < 4; ++i)
                #pragma unroll
                for (int j = 0; j < 4; ++j)
                    acc[i][j] = __builtin_amdgcn_mfma_f32_16x16x32_bf16(
                        af[i], bf_[j], acc[i][j], 0, 0, 0);
        }
    }

    // epilogue via LDS restage (32 rows x 132 fp32) -> vectorized stores
    const float* bias = (EPI == 3) ? (z ? bias1 : bias0) : nullptr;
    float* eps = (float*)smem;
    const int half = wv >> 1;
    const int lrow = tid >> 3;          // 0..31
    const int cseg = (tid & 7) * 16;    // 0..112
    const int gr_  = bm + (lrow >> 4) * 64 + (lrow & 15);
    #pragma unroll
    for (int i = 0; i < 4; ++i) {
        __syncthreads();
        #pragma unroll
        for (int j = 0; j < 4; ++j)
            #pragma unroll
            for (int r = 0; r < 4; ++r)
                eps[(half * 16 + quad * 4 + r) * 132 + wc + j * 16 + fr] = acc[i][j][r];
        __syncthreads();
        float vals[16];
        *(float4*)(vals +  0) = *(const float4*)(eps + lrow * 132 + cseg +  0);
        *(float4*)(vals +  4) = *(const float4*)(eps + lrow * 132 + cseg +  4);
        *(float4*)(vals +  8) = *(const float4*)(eps + lrow * 132 + cseg +  8);
        *(float4*)(vals + 12) = *(const float4*)(eps + lrow * 132 + cseg + 12);
        int gr = gr_ + i * 16;
        int gc = bn + cseg;
        if (EPI == 0) {
            float* dst = (float*)Cp + (size_t)z * cofs + (size_t)gr * ldc + gc;
            *(float4*)(dst +  0) = *(const float4*)(vals +  0);
            *(float4*)(dst +  4) = *(const float4*)(vals +  4);
            *(float4*)(dst +  8) = *(const float4*)(vals +  8);
            *(float4*)(dst + 12) = *(const float4*)(vals + 12);
        } else {
            unsigned short os[16];
            #pragma unroll
            for (int c = 0; c < 16; ++c) {
                float t = vals[c];
                if (EPI == 3) t = softplusf(t + bias[gc + c]);
                os[c] = f2bf(t);
            }
            unsigned short* dst = (unsigned short*)Cp + (size_t)z * cofs +
                                  (size_t)gr * ldc + gc;
            *(ushort4*)(dst +  0) = *(ushort4*)(os +  0);
            *(ushort4*)(dst +  4) = *(ushort4*)(os +  4);
            *(ushort4*)(dst +  8) = *(ushort4*)(os +  8);
            *(ushort4*)(dst + 12) = *(ushort4*)(os + 12);
        }
    }
}

// ---------------- x-proj split-K partials, grouped over dir ----------------
__global__ __launch_bounds__(256) void xproj_part_k(
    const __hip_bfloat16* __restrict__ A,
    const __hip_bfloat16* __restrict__ B,
    float* __restrict__ part)
{
    __shared__ __hip_bfloat16 smem[2 * 128 * 64];
    __hip_bfloat16* As = smem;
    __hip_bfloat16* Bs = smem + 128 * 64;
    const int tid  = threadIdx.x;
    const int ks   = blockIdx.x;
    const int bm   = blockIdx.y * 128;
    const int z    = blockIdx.z;
    const __hip_bfloat16* Az = A + (size_t)z * MR * DI;
    const __hip_bfloat16* Bz = B + (size_t)z * 128 * DI;
    const int kb   = ks * (DI / KS);
    const int wv   = tid >> 6;
    const int lane = tid & 63;
    const int wr   = (wv >> 1) * 64;
    const int wc   = (wv & 1) * 64;
    const int srow = wv * 32 + (lane >> 3);
    const int cg   = ((lane & 7) ^ (lane >> 3)) * 8;
    const int fr   = lane & 15;
    const int quad = lane >> 4;
    const int pc0  = (quad ^ (fr & 7)) * 8;
    const int pc1  = ((4 + quad) ^ (fr & 7)) * 8;

    f32x4 acc[4][4] = {};

    #pragma unroll
    for (int k0 = 0; k0 < DI / KS; k0 += 64) {
        __syncthreads();
        #pragma unroll
        for (int i = 0; i < 4; ++i) {
            int r = srow + i * 8;
            gl2lds16(Az + (size_t)(bm + r) * DI + kb + k0 + cg, As + wv * 2048 + i * 512);
            gl2lds16(Bz + (size_t)r * DI + kb + k0 + cg,        Bs + wv * 2048 + i * 512);
        }
        __syncthreads();
        #pragma unroll
        for (int kk = 0; kk < 2; ++kk) {
            const int pc = kk ? pc1 : pc0;
            bf16x8 af[4], bf_[4];
            #pragma unroll
            for (int i = 0; i < 4; ++i) {
                af[i]  = *(const bf16x8*)(As + (wr + i * 16 + fr) * 64 + pc);
                bf_[i] = *(const bf16x8*)(Bs + (wc + i * 16 + fr) * 64 + pc);
            }
            #pragma unroll
            for (int i = 0; i < 4; ++i)
                #pragma unroll
                for (int j = 0; j < 4; ++j)
                    acc[i][j] = __builtin_amdgcn_mfma_f32_16x16x32_bf16(
                        af[i], bf_[j], acc[i][j], 0, 0, 0);
        }
    }

    float* dst = part + ((size_t)z * KS + ks) * MR * XLD;
    const int er = quad * 4;
    #pragma unroll
    for (int i = 0; i < 4; ++i)
        #pragma unroll
        for (int j = 0; j < 4; ++j) {
            int row = bm + wr + i * 16 + er;
            int col = wc + j * 16 + fr;
            #pragma unroll
            for (int r = 0; r < 4; ++r)
                dst[(size_t)(row + r) * XLD + col] = acc[i][j][r];
        }
}

// ---------------- reduce x-proj partials -> xdb2 fp32 + dt-cols bf16 ----------------
__global__ __launch_bounds__(256) void xproj_reduce_k(
    const float* __restrict__ part, float* __restrict__ xdb,
    __hip_bfloat16* __restrict__ xdbt)
{
    int z = blockIdx.y;
    size_t idx = ((size_t)blockIdx.x * 256 + threadIdx.x) * 4;   // over MR*XLD
    const float* p = part + (size_t)z * KS * MR * XLD;
    float4 s = make_float4(0.f, 0.f, 0.f, 0.f);
    #pragma unroll
    for (int ks = 0; ks < KS; ++ks) {
        float4 v = *(const float4*)(p + (size_t)ks * MR * XLD + idx);
        s.x += v.x; s.y += v.y; s.z += v.z; s.w += v.w;
    }
    *(float4*)(xdb + (size_t)z * MR * XLD + idx) = s;
    int c = (int)(idx & (XLD - 1));
    if (c < 64) {
        size_t m = idx >> 7;
        ushort4 o;
        o.x = f2bf(s.x); o.y = f2bf(s.y); o.z = f2bf(s.z); o.w = f2bf(s.w);
        *(ushort4*)((unsigned short*)xdbt + (size_t)z * MR * 64 + m * 64 + c) = o;
    }
}

// ---------------- Depthwise conv (width 4) + SiLU, both dirs ----------------
__global__ __launch_bounds__(256) void conv_silu_k(
    const __hip_bfloat16* __restrict__ xz2,
    const float* __restrict__ fW, const float* __restrict__ fb,
    const float* __restrict__ bW, const float* __restrict__ bb_,
    __hip_bfloat16* __restrict__ xsb2)
{
    int dirv = blockIdx.y;
    int idx = blockIdx.x * 256 + threadIdx.x;   // over MR*DI
    int d = idx & (DI - 1);
    int m = idx >> 11;
    int t = m & (LL - 1);
    int bb = m >> 10;
    const float* w  = (dirv ? bW : fW) + d * 4;
    const __hip_bfloat16* xz = xz2 + (size_t)dirv * MR * 2 * DI;
    float acc = (dirv ? bb_ : fb)[d];
    if (dirv == 0) {
        #pragma unroll
        for (int k = 0; k < 4; ++k) {
            int tt = t - 3 + k;
            if (tt >= 0)
                acc = fmaf(w[k], bf2f(xz[(size_t)(bb * LL + tt) * (2 * DI) + d]), acc);
        }
    } else {
        #pragma unroll
        for (int k = 0; k < 4; ++k) {
            int tt = t + 3 - k;
            if (tt < LL)
                acc = fmaf(w[k], bf2f(xz[(size_t)(bb * LL + tt) * (2 * DI) + d]), acc);
        }
    }
    xsb2[(size_t)dirv * MR * DI + (size_t)m * DI + d] = __float2bfloat16(siluf(acc));
}

// ---------------- Chunked selective scan, both dirs ----------------
// A_log structurally log(tile(arange(1..17))) -> dA_s = r^(s+1), r = exp(-dt),
// guarded per-thread; exact path otherwise.
__global__ __launch_bounds__(256) void scan1_k(
    const __hip_bfloat16* __restrict__ dtf2, const __hip_bfloat16* __restrict__ xsb2,
    const float* __restrict__ xdb2,
    const float* __restrict__ fA, const float* __restrict__ bA,
    float* __restrict__ hend, float* __restrict__ aprod, int G, int Cn)
{
    int d  = blockIdx.x * 256 + threadIdx.x;
    int bb = blockIdx.y;
    int zz = blockIdx.z;
    int dirv = (zz >= G) ? 1 : 0;
    int g = zz - (dirv ? G : 0);
    const float* A_log = dirv ? bA : fA;
    const __hip_bfloat16* dtf = dtf2 + (size_t)dirv * MR * DI;
    const __hip_bfloat16* xs = xsb2 + (size_t)dirv * MR * DI;
    const float* xdb = xdb2 + (size_t)dirv * MR * XLD;
    size_t hoff = (size_t)dirv * G * (NB * DI * DST);

    float Ad[DST], h[DST], ap[DST];
    bool pw = true;
    #pragma unroll
    for (int s = 0; s < DST; ++s) {
        Ad[s] = -__expf(A_log[d * DST + s]);
        pw = pw && (fabsf(Ad[s] + (float)(s + 1)) < 1e-3f * (s + 1));
        h[s] = 0.f; ap[s] = 1.f;
    }
    int i0 = g * Cn;
    for (int i = 0; i < Cn; ++i) {
        int ii = i0 + i;
        int t = dirv ? (LL - 1 - ii) : ii;
        size_t m = (size_t)bb * LL + t;
        float dtv = bf2f(dtf[m * DI + d]);
        float xv  = bf2f(xs[m * DI + d]);
        const float* bc = xdb + m * XLD;
        float dtx = dtv * xv;
        float dAv[DST];
        if (pw) {
            float r = __expf(-dtv);
            float a = r;
            #pragma unroll
            for (int s = 0; s < DST; ++s) { dAv[s] = a; a *= r; }
        } else {
            #pragma unroll
            for (int s = 0; s < DST; ++s) dAv[s] = __expf(dtv * Ad[s]);
        }
        #pragma unroll
        for (int s = 0; s < DST; ++s) {
            h[s] = fmaf(h[s], dAv[s], dtx * bc[64 + s]);
            ap[s] *= dAv[s];
        }
    }
    size_t base = hoff + ((size_t)(g * NB + bb) * DI + d) * DST;
    #pragma unroll
    for (int s = 0; s < DST; s += 4) {
        *(float4*)(hend  + base + s) = make_float4(h[s], h[s+1], h[s+2], h[s+3]);
        *(float4*)(aprod + base + s) = make_float4(ap[s], ap[s+1], ap[s+2], ap[s+3]);
    }
}

__global__ __launch_bounds__(256) void scan2_k(
    float* __restrict__ hend, const float* __restrict__ aprod, int G)
{
    int dirv = blockIdx.y;
    int idx = blockIdx.x * 256 + threadIdx.x;   // over NB*DI*DST
    const int slab = NB * DI * DST;
    size_t hoff = (size_t)dirv * G * slab;
    float carry = 0.f;
    for (int g = 0; g < G; ++g) {
        size_t off = hoff + (size_t)g * slab + idx;
        float a = aprod[off];
        float e = hend[off];
        hend[off] = carry;
        carry = fmaf(a, carry, e);
    }
}

__global__ __launch_bounds__(256) void scan3_k(
    const __hip_bfloat16* __restrict__ dtf2, const __hip_bfloat16* __restrict__ xsb2,
    const float* __restrict__ xdb2, const __hip_bfloat16* __restrict__ xz2,
    const float* __restrict__ fA, const float* __restrict__ bA,
    const float* __restrict__ fD, const float* __restrict__ bD,
    const float* __restrict__ hin, __hip_bfloat16* __restrict__ ycat, int G, int Cn)
{
    int d  = blockIdx.x * 256 + threadIdx.x;
    int bb = blockIdx.y;
    int zz = blockIdx.z;
    int dirv = (zz >= G) ? 1 : 0;
    int g = zz - (dirv ? G : 0);
    const float* A_log = dirv ? bA : fA;
    const float* Dskip = dirv ? bD : fD;
    const __hip_bfloat16* dtf = dtf2 + (size_t)dirv * MR * DI;
    const __hip_bfloat16* xs = xsb2 + (size_t)dirv * MR * DI;
    const float* xdb = xdb2 + (size_t)dirv * MR * XLD;
    const __hip_bfloat16* xz = xz2 + (size_t)dirv * MR * 2 * DI;
    size_t hoff = (size_t)dirv * G * (NB * DI * DST);

    float Ad[DST], h[DST];
    bool pw = true;
    size_t base = hoff + ((size_t)(g * NB + bb) * DI + d) * DST;
    #pragma unroll
    for (int s = 0; s < DST; ++s) {
        Ad[s] = -__expf(A_log[d * DST + s]);
        pw = pw && (fabsf(Ad[s] + (float)(s + 1)) < 1e-3f * (s + 1));
        h[s] = hin[base + s];
    }
    float Dsk = Dskip[d];
    int i0 = g * Cn;
    for (int i = 0; i < Cn; ++i) {
        int ii = i0 + i;
        int t = dirv ? (LL - 1 - ii) : ii;
        size_t m = (size_t)bb * LL + t;
        float dtv = bf2f(dtf[m * DI + d]);
        float xv  = bf2f(xs[m * DI + d]);
        const float* bc = xdb + m * XLD;
        float dtx = dtv * xv;
        float dAv[DST];
        if (pw) {
            float r = __expf(-dtv);
            float a = r;
            #pragma unroll
            for (int s = 0; s < DST; ++s) { dAv[s] = a; a *= r; }
        } else {
            #pragma unroll
            for (int s = 0; s < DST; ++s) dAv[s] = __expf(dtv * Ad[s]);
        }
        float yv = 0.f;
        #pragma unroll
        for (int s = 0; s < DST; ++s) {
            h[s] = fmaf(h[s], dAv[s], dtx * bc[64 + s]);
            yv = fmaf(h[s], bc[80 + s], yv);
        }
        float zv = bf2f(xz[m * (2 * DI) + DI + d]);
        ycat[m * (2 * DI) + (size_t)dirv * DI + d] =
            __float2bfloat16((yv + xv * Dsk) * siluf(zv));
    }
}

// fallback monolithic scan (both dirs) if ws too small for chunk bufs
__global__ __launch_bounds__(256) void scan_mono_k(
    const __hip_bfloat16* __restrict__ dtf2, const __hip_bfloat16* __restrict__ xsb2,
    const float* __restrict__ xdb2, const __hip_bfloat16* __restrict__ xz2,
    const float* __restrict__ fA, const float* __restrict__ bA,
    const float* __restrict__ fD, const float* __restrict__ bD,
    __hip_bfloat16* __restrict__ ycat)
{
    int d  = blockIdx.x * 256 + threadIdx.x;
    int bb = blockIdx.y;
    int dirv = blockIdx.z;
    const float* A_log = dirv ? bA : fA;
    const float* Dskip = dirv ? bD : fD;
    const __hip_bfloat16* dtf = dtf2 + (size_t)dirv * MR * DI;
    const __hip_bfloat16* xs = xsb2 + (size_t)dirv * MR * DI;
    const float* xdb = xdb2 + (size_t)dirv * MR * XLD;
    const __hip_bfloat16* xz = xz2 + (size_t)dirv * MR * 2 * DI;
    float Ad[DST], h[DST];
    #pragma unroll
    for (int s = 0; s < DST; ++s) { Ad[s] = -__expf(A_log[d * DST + s]); h[s] = 0.f; }
    float Dsk = Dskip[d];
    for (int i = 0; i < LL; ++i) {
        int t = dirv ? (LL - 1 - i) : i;
        size_t m = (size_t)bb * LL + t;
        float dtv = bf2f(dtf[m * DI + d]);
        float xv  = bf2f(xs[m * DI + d]);
        const float* bc = xdb + m * XLD;
        float dtx = dtv * xv;
        float yv = 0.f;
        #pragma unroll
        for (int s = 0; s < DST; ++s) {
            float dA = __expf(dtv * Ad[s]);
            h[s] = fmaf(h[s], dA, dtx * bc[64 + s]);
            yv = fmaf(h[s], bc[80 + s], yv);
        }
        float zv = bf2f(xz[m * (2 * DI) + DI + d]);
        ycat[m * (2 * DI) + (size_t)dirv * DI + d] =
            __float2bfloat16((yv + xv * Dsk) * siluf(zv));
    }
}

// ---------------- final reduce: out = x + proj_b + sum_z part[z] ----------------
__global__ __launch_bounds__(256) void final_reduce_k(
    const float* __restrict__ part, const float* __restrict__ x,
    const float* __restrict__ proj_b, float* __restrict__ out)
{
    size_t idx = ((size_t)blockIdx.x * 256 + threadIdx.x) * 4;   // over MR*DM
    float4 s = make_float4(0.f, 0.f, 0.f, 0.f);
    #pragma unroll
    for (int z = 0; z < 4; ++z) {
        float4 v = *(const float4*)(part + (size_t)z * MR * DM + idx);
        s.x += v.x; s.y += v.y; s.z += v.z; s.w += v.w;
    }
    float4 xv = *(const float4*)(x + idx);
    float4 pb = *(const float4*)(proj_b + (idx & (DM - 1)));
    float4 o;
    o.x = xv.x + pb.x + s.x;
    o.y = xv.y + pb.y + s.y;
    o.z = xv.z + pb.z + s.z;
    o.w = xv.w + pb.w + s.w;
    *(float4*)(out + idx) = o;
}

// ---------------- Launch ----------------
extern "C" void kernel_launch(void* const* d_in, const int* in_sizes, int n_in,
                              void* d_out, int out_size, void* d_ws, size_t ws_size,
                              hipStream_t stream)
{
    const float* x      = (const float*)d_in[0];
    const float* ln_w   = (const float*)d_in[1];
    const float* ln_b   = (const float*)d_in[2];
    const float* f_inW    = (const float*)d_in[3];
    const float* f_convW  = (const float*)d_in[4];
    const float* f_convb  = (const float*)d_in[5];
    const float* f_xprojW = (const float*)d_in[6];
    const float* f_dtW    = (const float*)d_in[7];
    const float* f_dtb    = (const float*)d_in[8];
    const float* f_A_log  = (const float*)d_in[9];
    const float* f_Dskip  = (const float*)d_in[10];
    const float* f_outW   = (const float*)d_in[11];
    const float* b_inW    = (const float*)d_in[12];
    const float* b_convW  = (const float*)d_in[13];
    const float* b_convb  = (const float*)d_in[14];
    const float* b_xprojW = (const float*)d_in[15];
    const float* b_dtW    = (const float*)d_in[16];
    const float* b_dtb    = (const float*)d_in[17];
    const float* b_A_log  = (const float*)d_in[18];
    const float* b_Dskip  = (const float*)d_in[19];
    const float* b_outW   = (const float*)d_in[20];
    const float* proj_W = (const float*)d_in[21];
    const float* proj_b = (const float*)d_in[22];

    float* ws = (float*)d_ws;
    size_t o = 0;
    // xz2 region (8,388,608 floats): wot [2][DI][DM] bf16 during prep (dead
    // after Wcat GEMM), then xz2 bf16 [2][MR][2DI], then final split-K fp32
    // partials [4][MR][DM] (xz2 dead after scan3).
    __hip_bfloat16* xz2  = (__hip_bfloat16*)(ws + o);
    __hip_bfloat16* wot  = xz2;
    float* fpart = ws + o;
    o += (size_t)2 * MR * 2 * DI / 2;
    __hip_bfloat16* xsb2 = (__hip_bfloat16*)(ws + o); o += (size_t)2 * MR * DI / 2;
    // ycat region: x-proj split-K fp32 partials first, then ycat bf16 [MR][2DI].
    __hip_bfloat16* ycat = (__hip_bfloat16*)(ws + o);
    float* xpart = ws + o;
    o += (size_t)MR * 2 * DI / 2;
    float* xdb2 = ws + o; o += (size_t)2 * MR * XLD;
    __hip_bfloat16* xdbt = (__hip_bfloat16*)(ws + o); o += (size_t)2 * MR * 64 / 2;
    __hip_bfloat16* dtfb = (__hip_bfloat16*)(ws + o); o += (size_t)2 * MR * DI / 2;
    __hip_bfloat16* nb = (__hip_bfloat16*)(ws + o); o += (size_t)MR * DM / 2;
    __hip_bfloat16* warena = (__hip_bfloat16*)(ws + o); o += 15466496 / 2;
    float* hbuf = ws + o;
    size_t base_floats = o;

    __hip_bfloat16* wbi  = warena;               // [2][2DI][DM]    8,388,608
    __hip_bfloat16* pwb  = warena +  8388608;    // [DM][2DM]       2,097,152
    __hip_bfloat16* wdt  = warena + 10485760;    // [2][DI][64]       262,144
    __hip_bfloat16* wpb2 = warena + 10747904;    // [2][128][DI]      524,288
    __hip_bfloat16* wcat = warena + 11272192;    // [DM][2DI]       4,194,304

    const size_t slab = (size_t)NB * DI * DST;   // 65536
    int G = 32;
    while (G > 4 && (base_floats + 4ull * G * slab) * 4 > ws_size) G >>= 1;
    int useChunks = ((base_floats + 4ull * G * slab) * 4 <= ws_size);
    float* hend  = hbuf;
    float* aprod = hbuf + 2ull * G * slab;
    int Cn = useChunks ? LL / G : LL;

    // 1: mega-prep (weight cvts + transpose + layernorm)
    prep_k<<<13696, 256, 0, stream>>>(
        f_inW, b_inW, proj_W, f_dtW, b_dtW, warena,
        f_xprojW, b_xprojW, wpb2,
        f_outW, b_outW, wot,
        x, ln_w, ln_b, nb);

    // 2: Wcat[e, z*DI+d] = sum_{e'} proj_W[e, z*DM+e'] * outW_z[e', d]
    gemm_gl<1><<<dim3(DI / 128, DM / 128, 2), 256, 0, stream>>>(
        pwb, 2 * DM, (size_t)DM, wot, DM, (size_t)DI * DM,
        wcat, 2 * DI, (size_t)DI, DM, nullptr, nullptr);

    // 3: in-proj both dirs (overwrites wot)
    gemm_gl<1><<<dim3((2 * DI) / 128, MR / 128, 2), 256, 0, stream>>>(
        nb, DM, 0, wbi, DM, (size_t)2 * DI * DM,
        xz2, 2 * DI, (size_t)MR * 2 * DI, DM, nullptr, nullptr);

    // 4: conv + silu both dirs -> xsb2
    conv_silu_k<<<dim3((MR * DI) / 256, 2), 256, 0, stream>>>(
        xz2, f_convW, f_convb, b_convW, b_convb, xsb2);

    // 5-6: x-proj split-K + reduce
    xproj_part_k<<<dim3(KS, MR / 128, 2), 256, 0, stream>>>(xsb2, wpb2, xpart);
    xproj_reduce_k<<<dim3((MR * XLD) / 1024, 2), 256, 0, stream>>>(xpart, xdb2, xdbt);

    // 7: dt-proj both dirs: dtfb = softplus(xdbt @ dtW^T + dtb) (bf16)
    gemm_gl<3><<<dim3(DI / 128, MR / 128, 2), 256, 0, stream>>>(
        xdbt, 64, (size_t)MR * 64, wdt, 64, (size_t)DI * 64,
        dtfb, DI, (size_t)MR * DI, 64, f_dtb, b_dtb);

    // 8-10: selective scan both dirs -> ycat [MR][2*DI]
    if (useChunks) {
        scan1_k<<<dim3(DI / 256, NB, 2 * G), 256, 0, stream>>>(
            dtfb, xsb2, xdb2, f_A_log, b_A_log, hend, aprod, G, Cn);
        scan2_k<<<dim3((NB * DI * DST) / 256, 2), 256, 0, stream>>>(hend, aprod, G);
        scan3_k<<<dim3(DI / 256, NB, 2 * G), 256, 0, stream>>>(
            dtfb, xsb2, xdb2, xz2, f_A_log, b_A_log, f_Dskip, b_Dskip,
            hend, ycat, G, Cn);
    } else {
        scan_mono_k<<<dim3(DI / 256, NB, 2), 256, 0, stream>>>(
            dtfb, xsb2, xdb2, xz2, f_A_log, b_A_log, f_Dskip, b_Dskip, ycat);
    }

    // 11: final split-K GEMM -> fp32 partials (overwrites xz2 region)
    gemm_gl<0><<<dim3(DM / 128, MR / 128, 4), 256, 0, stream>>>(
        ycat, 2 * DI, 1024, wcat, 2 * DI, 1024,
        fpart, DM, (size_t)MR * DM, 1024, nullptr, nullptr);

    // 12: out = x + proj_b + sum_z fpart
    final_reduce_k<<<(MR * DM) / 1024, 256, 0, stream>>>(
        fpart, x, proj_b, (float*)d_out);
}

// Round 10
// 421.624 us; speedup vs baseline: 1.0227x; 1.0024x over previous
//
#include <hip/hip_runtime.h>
#include <hip/hip_bf16.h>
#include <math.h>

#define DM   1024   // d_model
#define DI   2048   // d_inner
#define DTR  64     // dt_rank
#define DST  16     // d_state
#define NB   2      // batch
#define LL   1024   // seq len
#define MR   (NB*LL)  // 2048 rows
#define XLD  128    // xdb padded leading dim
#define KS   8      // split-K factor for x-proj

typedef __bf16 bf16x8 __attribute__((ext_vector_type(8)));
typedef float  f32x4  __attribute__((ext_vector_type(4)));

__device__ __forceinline__ float siluf(float x) { return x / (1.f + __expf(-x)); }
__device__ __forceinline__ float softplusf(float x) {
    return fmaxf(x, 0.f) + log1pf(__expf(-fabsf(x)));
}
__device__ __forceinline__ unsigned short f2bf(float f) {
    __hip_bfloat16 h = __float2bfloat16(f);
    return *reinterpret_cast<unsigned short*>(&h);
}
__device__ __forceinline__ float bf2f(__hip_bfloat16 h) { return __bfloat162float(h); }

__device__ __forceinline__ void gl2lds16(const __hip_bfloat16* g, __hip_bfloat16* l)
{
    __builtin_amdgcn_global_load_lds(
        (const __attribute__((address_space(1))) unsigned int*)g,
        (__attribute__((address_space(3))) unsigned int*)l, 16, 0, 0);
}

// ---------------- mega-prep: weight cvts + transpose + layernorm ----------------
// sections by blockIdx.x:
//   [0, 10496)        cvt_all: fp32->bf16 of inW x2, proj_W, dtW x2 into warena
//   [10496, 10624)    pad96: xprojW -> bf16 padded to 128 rows, both dirs
//   [10624, 11648)    transpose: outW [DM][DI] -> [DI][DM] bf16, both dirs
//   [11648, 13696)    layernorm -> nb bf16
__global__ __launch_bounds__(256) void prep_k(
    const float* __restrict__ s0, const float* __restrict__ s1,
    const float* __restrict__ s2, const float* __restrict__ s3,
    const float* __restrict__ s4, __hip_bfloat16* __restrict__ warena,
    const float* __restrict__ fx, const float* __restrict__ bx,
    __hip_bfloat16* __restrict__ wpb2,
    const float* __restrict__ fo, const float* __restrict__ bo,
    __hip_bfloat16* __restrict__ wot,
    const float* __restrict__ x, const float* __restrict__ lnw,
    const float* __restrict__ lnb, __hip_bfloat16* __restrict__ nb)
{
    __shared__ float pshm[64 * 65];
    const int b = blockIdx.x;
    const int tid = threadIdx.x;

    if (b < 10496) {
        long idx = (long)b * 1024 + tid * 4;
        const float* src; long off;
        if      (idx <  4194304L) { src = s0; off = idx; }
        else if (idx <  8388608L) { src = s1; off = idx -  4194304L; }
        else if (idx < 10485760L) { src = s2; off = idx -  8388608L; }
        else if (idx < 10616832L) { src = s3; off = idx - 10485760L; }
        else                      { src = s4; off = idx - 10616832L; }
        float4 v = *(const float4*)(src + off);
        ushort4 o;
        o.x = f2bf(v.x); o.y = f2bf(v.y); o.z = f2bf(v.z); o.w = f2bf(v.w);
        *(ushort4*)((unsigned short*)warena + idx) = o;
    } else if (b < 10624) {
        int t = b - 10496;
        int z = t >> 6;
        const float* in = z ? bx : fx;
        int idx = ((t & 63) * 256 + tid) * 4;   // over 128*DI
        int row = idx >> 11;
        ushort4 o = make_ushort4(0, 0, 0, 0);
        if (row < 96) {
            float4 v = *(const float4*)(in + idx);
            o.x = f2bf(v.x); o.y = f2bf(v.y); o.z = f2bf(v.z); o.w = f2bf(v.w);
        }
        *(ushort4*)((unsigned short*)wpb2 + (size_t)z * 128 * DI + idx) = o;
    } else if (b < 11648) {
        int t = b - 10624;
        int z = t >> 9; t &= 511;
        const float* src = z ? bo : fo;
        int c0 = (t & 31) * 64;    // col in src (DI dim)
        int r0 = (t >> 5) * 64;    // row in src (DM dim)
        int tc = tid & 63;
        int tr = tid >> 6;
        #pragma unroll
        for (int ii = 0; ii < 16; ++ii) {
            int rl = tr + ii * 4;
            pshm[tc * 65 + rl] = src[(size_t)(r0 + rl) * DI + c0 + tc];
        }
        __syncthreads();
        __hip_bfloat16* dst = wot + (size_t)z * DI * DM;
        #pragma unroll
        for (int ii = 0; ii < 16; ++ii) {
            int cl = tr + ii * 4;
            dst[(size_t)(c0 + cl) * DM + r0 + tc] = __float2bfloat16(pshm[cl * 65 + tc]);
        }
    } else {
        int row = b - 11648;
        const float* xr = x + (size_t)row * DM;
        float4 v = *(const float4*)(xr + tid * 4);
        float s = v.x + v.y + v.z + v.w;
        float q = v.x*v.x + v.y*v.y + v.z*v.z + v.w*v.w;
        #pragma unroll
        for (int off = 32; off > 0; off >>= 1) {
            s += __shfl_xor(s, off, 64);
            q += __shfl_xor(q, off, 64);
        }
        int wv = tid >> 6;
        if ((tid & 63) == 0) { pshm[wv] = s; pshm[8 + wv] = q; }
        __syncthreads();
        s = pshm[0] + pshm[1] + pshm[2] + pshm[3];
        q = pshm[8] + pshm[9] + pshm[10] + pshm[11];
        float mu  = s * (1.f / DM);
        float var = q * (1.f / DM) - mu * mu;
        float rstd = rsqrtf(var + 1e-5f);
        float4 wv4 = *(const float4*)(lnw + tid * 4);
        float4 bv4 = *(const float4*)(lnb + tid * 4);
        ushort4 o;
        o.x = f2bf((v.x - mu) * rstd * wv4.x + bv4.x);
        o.y = f2bf((v.y - mu) * rstd * wv4.y + bv4.y);
        o.z = f2bf((v.z - mu) * rstd * wv4.z + bv4.z);
        o.w = f2bf((v.w - mu) * rstd * wv4.w + bv4.w);
        *(ushort4*)((unsigned short*)nb + (size_t)row * DM + tid * 4) = o;
    }
}

// ---------------- merged in-proj + Wcat dispatch ----------------
// z in {0,1}: xz2[z] = nb @ inW[z]^T    (grid 32x16 active)
// z in {2,3}: wcat[:, (z-2)*DI:+DI] = proj_W[:, (z-2)*DM:+DM] @ outW[z-2]^T
//             (grid 16x8 active; other blocks exit)
// All K=1024, ldc=4096, bf16 out; LDS-restaged vectorized epilogue.
__global__ __launch_bounds__(256) void inproj_wcat_k(
    const __hip_bfloat16* __restrict__ nb,  const __hip_bfloat16* __restrict__ wbi,
    __hip_bfloat16* __restrict__ xz2,
    const __hip_bfloat16* __restrict__ pwb, const __hip_bfloat16* __restrict__ wot,
    __hip_bfloat16* __restrict__ wcat)
{
    __shared__ __hip_bfloat16 smem[2 * 128 * 64];
    const int z  = blockIdx.z;
    const int bxv = blockIdx.x, byv = blockIdx.y;
    if (z >= 2 && (bxv >= 16 || byv >= 8)) return;

    const __hip_bfloat16* Az;
    const __hip_bfloat16* Bz;
    __hip_bfloat16* Cz;
    int lda;
    if (z < 2) {
        Az = nb;                                lda = DM;
        Bz = wbi + (size_t)z * 2 * DI * DM;
        Cz = xz2 + (size_t)z * MR * 2 * DI;
    } else {
        Az = pwb + (size_t)(z - 2) * DM;        lda = 2 * DM;
        Bz = wot + (size_t)(z - 2) * DI * DM;
        Cz = wcat + (size_t)(z - 2) * DI;
    }
    const int ldb = DM, ldc = 2 * DI, K = DM;

    __hip_bfloat16* As = smem;
    __hip_bfloat16* Bs = smem + 128 * 64;
    const int tid  = threadIdx.x;
    const int bm   = byv * 128;
    const int bn   = bxv * 128;
    const int wv   = tid >> 6;
    const int lane = tid & 63;
    const int wr   = (wv >> 1) * 64;
    const int wc   = (wv & 1) * 64;
    const int srow = wv * 32 + (lane >> 3);
    const int cg   = ((lane & 7) ^ (lane >> 3)) * 8;
    const int fr   = lane & 15;
    const int quad = lane >> 4;
    const int pc0  = (quad ^ (fr & 7)) * 8;
    const int pc1  = ((4 + quad) ^ (fr & 7)) * 8;

    f32x4 acc[4][4] = {};

    for (int k0 = 0; k0 < K; k0 += 64) {
        __syncthreads();
        #pragma unroll
        for (int i = 0; i < 4; ++i) {
            int r = srow + i * 8;
            gl2lds16(Az + (size_t)(bm + r) * lda + k0 + cg, As + wv * 2048 + i * 512);
            gl2lds16(Bz + (size_t)(bn + r) * ldb + k0 + cg, Bs + wv * 2048 + i * 512);
        }
        __syncthreads();
        #pragma unroll
        for (int kk = 0; kk < 2; ++kk) {
            const int pc = kk ? pc1 : pc0;
            bf16x8 af[4], bf_[4];
            #pragma unroll
            for (int i = 0; i < 4; ++i) {
                af[i]  = *(const bf16x8*)(As + (wr + i * 16 + fr) * 64 + pc);
                bf_[i] = *(const bf16x8*)(Bs + (wc + i * 16 + fr) * 64 + pc);
            }
            #pragma unroll
            for (int i = 0; i < 4; ++i)
                #pragma unroll
                for (int j = 0; j < 4; ++j)
                    acc[i][j] = __builtin_amdgcn_mfma_f32_16x16x32_bf16(
                        af[i], bf_[j], acc[i][j], 0, 0, 0);
        }
    }

    float* eps = (float*)smem;
    const int half = wv >> 1;
    const int lrow = tid >> 3;
    const int cseg = (tid & 7) * 16;
    const int gr_  = bm + (lrow >> 4) * 64 + (lrow & 15);
    #pragma unroll
    for (int i = 0; i < 4; ++i) {
        __syncthreads();
        #pragma unroll
        for (int j = 0; j < 4; ++j)
            #pragma unroll
            for (int r = 0; r < 4; ++r)
                eps[(half * 16 + quad * 4 + r) * 132 + wc + j * 16 + fr] = acc[i][j][r];
        __syncthreads();
        float vals[16];
        *(float4*)(vals +  0) = *(const float4*)(eps + lrow * 132 + cseg +  0);
        *(float4*)(vals +  4) = *(const float4*)(eps + lrow * 132 + cseg +  4);
        *(float4*)(vals +  8) = *(const float4*)(eps + lrow * 132 + cseg +  8);
        *(float4*)(vals + 12) = *(const float4*)(eps + lrow * 132 + cseg + 12);
        int gr = gr_ + i * 16;
        int gc = bn + cseg;
        unsigned short os[16];
        #pragma unroll
        for (int c = 0; c < 16; ++c) os[c] = f2bf(vals[c]);
        unsigned short* dst = (unsigned short*)Cz + (size_t)gr * ldc + gc;
        *(ushort4*)(dst +  0) = *(ushort4*)(os +  0);
        *(ushort4*)(dst +  4) = *(ushort4*)(os +  4);
        *(ushort4*)(dst +  8) = *(ushort4*)(os +  8);
        *(ushort4*)(dst + 12) = *(ushort4*)(os + 12);
    }
}

// ---------------- bf16 MFMA GEMM with global_load_lds staging ----------------
// EPI: 0 = fp32 store, 1 = bf16 store, 3 = softplus(v+bias_z[n]) bf16 store.
template<int EPI>
__global__ __launch_bounds__(256) void gemm_gl(
    const __hip_bfloat16* __restrict__ A, int lda, size_t aofs,
    const __hip_bfloat16* __restrict__ B, int ldb, size_t bofs,
    void* __restrict__ Cp, int ldc, size_t cofs, int K,
    const float* __restrict__ bias0, const float* __restrict__ bias1)
{
    __shared__ __hip_bfloat16 smem[2 * 128 * 64];
    __hip_bfloat16* As = smem;
    __hip_bfloat16* Bs = smem + 128 * 64;
    const int tid  = threadIdx.x;
    const int z    = blockIdx.z;
    const int bm   = blockIdx.y * 128;
    const int bn   = blockIdx.x * 128;
    const __hip_bfloat16* Az = A + (size_t)z * aofs;
    const __hip_bfloat16* Bz = B + (size_t)z * bofs;
    const int wv   = tid >> 6;
    const int lane = tid & 63;
    const int wr   = (wv >> 1) * 64;
    const int wc   = (wv & 1) * 64;
    const int srow = wv * 32 + (lane >> 3);
    const int cg   = ((lane & 7) ^ (lane >> 3)) * 8;
    const int fr   = lane & 15;
    const int quad = lane >> 4;
    const int pc0  = (quad ^ (fr & 7)) * 8;
    const int pc1  = ((4 + quad) ^ (fr & 7)) * 8;

    f32x4 acc[4][4] = {};

    for (int k0 = 0; k0 < K; k0 += 64) {
        __syncthreads();
        #pragma unroll
        for (int i = 0; i < 4; ++i) {
            int r = srow + i * 8;
            gl2lds16(Az + (size_t)(bm + r) * lda + k0 + cg, As + wv * 2048 + i * 512);
            gl2lds16(Bz + (size_t)(bn + r) * ldb + k0 + cg, Bs + wv * 2048 + i * 512);
        }
        __syncthreads();
        #pragma unroll
        for (int kk = 0; kk < 2; ++kk) {
            const int pc = kk ? pc1 : pc0;
            bf16x8 af[4], bf_[4];
            #pragma unroll
            for (int i = 0; i < 4; ++i) {
                af[i]  = *(const bf16x8*)(As + (wr + i * 16 + fr) * 64 + pc);
                bf_[i] = *(const bf16x8*)(Bs + (wc + i * 16 + fr) * 64 + pc);
            }
            #pragma unroll
            for (int i = 0; i < 4; ++i)
                #pragma unroll
                for (int j = 0; j < 4; ++j)
                    acc[i][j] = __builtin_amdgcn_mfma_f32_16x16x32_bf16(
                        af[i], bf_[j], acc[i][j], 0, 0, 0);
        }
    }

    const float* bias = (EPI == 3) ? (z ? bias1 : bias0) : nullptr;
    float* eps = (float*)smem;
    const int half = wv >> 1;
    const int lrow = tid >> 3;
    const int cseg = (tid & 7) * 16;
    const int gr_  = bm + (lrow >> 4) * 64 + (lrow & 15);
    #pragma unroll
    for (int i = 0; i < 4; ++i) {
        __syncthreads();
        #pragma unroll
        for (int j = 0; j < 4; ++j)
            #pragma unroll
            for (int r = 0; r < 4; ++r)
                eps[(half * 16 + quad * 4 + r) * 132 + wc + j * 16 + fr] = acc[i][j][r];
        __syncthreads();
        float vals[16];
        *(float4*)(vals +  0) = *(const float4*)(eps + lrow * 132 + cseg +  0);
        *(float4*)(vals +  4) = *(const float4*)(eps + lrow * 132 + cseg +  4);
        *(float4*)(vals +  8) = *(const float4*)(eps + lrow * 132 + cseg +  8);
        *(float4*)(vals + 12) = *(const float4*)(eps + lrow * 132 + cseg + 12);
        int gr = gr_ + i * 16;
        int gc = bn + cseg;
        if (EPI == 0) {
            float* dst = (float*)Cp + (size_t)z * cofs + (size_t)gr * ldc + gc;
            *(float4*)(dst +  0) = *(const float4*)(vals +  0);
            *(float4*)(dst +  4) = *(const float4*)(vals +  4);
            *(float4*)(dst +  8) = *(const float4*)(vals +  8);
            *(float4*)(dst + 12) = *(const float4*)(vals + 12);
        } else {
            unsigned short os[16];
            #pragma unroll
            for (int c = 0; c < 16; ++c) {
                float t = vals[c];
                if (EPI == 3) t = softplusf(t + bias[gc + c]);
                os[c] = f2bf(t);
            }
            unsigned short* dst = (unsigned short*)Cp + (size_t)z * cofs +
                                  (size_t)gr * ldc + gc;
            *(ushort4*)(dst +  0) = *(ushort4*)(os +  0);
            *(ushort4*)(dst +  4) = *(ushort4*)(os +  4);
            *(ushort4*)(dst +  8) = *(ushort4*)(os +  8);
            *(ushort4*)(dst + 12) = *(ushort4*)(os + 12);
        }
    }
}

// ---------------- x-proj split-K partials, grouped over dir ----------------
__global__ __launch_bounds__(256) void xproj_part_k(
    const __hip_bfloat16* __restrict__ A,
    const __hip_bfloat16* __restrict__ B,
    float* __restrict__ part)
{
    __shared__ __hip_bfloat16 smem[2 * 128 * 64];
    __hip_bfloat16* As = smem;
    __hip_bfloat16* Bs = smem + 128 * 64;
    const int tid  = threadIdx.x;
    const int ks   = blockIdx.x;
    const int bm   = blockIdx.y * 128;
    const int z    = blockIdx.z;
    const __hip_bfloat16* Az = A + (size_t)z * MR * DI;
    const __hip_bfloat16* Bz = B + (size_t)z * 128 * DI;
    const int kb   = ks * (DI / KS);
    const int wv   = tid >> 6;
    const int lane = tid & 63;
    const int wr   = (wv >> 1) * 64;
    const int wc   = (wv & 1) * 64;
    const int srow = wv * 32 + (lane >> 3);
    const int cg   = ((lane & 7) ^ (lane >> 3)) * 8;
    const int fr   = lane & 15;
    const int quad = lane >> 4;
    const int pc0  = (quad ^ (fr & 7)) * 8;
    const int pc1  = ((4 + quad) ^ (fr & 7)) * 8;

    f32x4 acc[4][4] = {};

    #pragma unroll
    for (int k0 = 0; k0 < DI / KS; k0 += 64) {
        __syncthreads();
        #pragma unroll
        for (int i = 0; i < 4; ++i) {
            int r = srow + i * 8;
            gl2lds16(Az + (size_t)(bm + r) * DI + kb + k0 + cg, As + wv * 2048 + i * 512);
            gl2lds16(Bz + (size_t)r * DI + kb + k0 + cg,        Bs + wv * 2048 + i * 512);
        }
        __syncthreads();
        #pragma unroll
        for (int kk = 0; kk < 2; ++kk) {
            const int pc = kk ? pc1 : pc0;
            bf16x8 af[4], bf_[4];
            #pragma unroll
            for (int i = 0; i < 4; ++i) {
                af[i]  = *(const bf16x8*)(As + (wr + i * 16 + fr) * 64 + pc);
                bf_[i] = *(const bf16x8*)(Bs + (wc + i * 16 + fr) * 64 + pc);
            }
            #pragma unroll
            for (int i = 0; i < 4; ++i)
                #pragma unroll
                for (int j = 0; j < 4; ++j)
                    acc[i][j] = __builtin_amdgcn_mfma_f32_16x16x32_bf16(
                        af[i], bf_[j], acc[i][j], 0, 0, 0);
        }
    }

    float* dst = part + ((size_t)z * KS + ks) * MR * XLD;
    const int er = quad * 4;
    #pragma unroll
    for (int i = 0; i < 4; ++i)
        #pragma unroll
        for (int j = 0; j < 4; ++j) {
            int row = bm + wr + i * 16 + er;
            int col = wc + j * 16 + fr;
            #pragma unroll
            for (int r = 0; r < 4; ++r)
                dst[(size_t)(row + r) * XLD + col] = acc[i][j][r];
        }
}

// ---------------- reduce x-proj partials -> xdb2 fp32 + dt-cols bf16 ----------------
__global__ __launch_bounds__(256) void xproj_reduce_k(
    const float* __restrict__ part, float* __restrict__ xdb,
    __hip_bfloat16* __restrict__ xdbt)
{
    int z = blockIdx.y;
    size_t idx = ((size_t)blockIdx.x * 256 + threadIdx.x) * 4;   // over MR*XLD
    const float* p = part + (size_t)z * KS * MR * XLD;
    float4 s = make_float4(0.f, 0.f, 0.f, 0.f);
    #pragma unroll
    for (int ks = 0; ks < KS; ++ks) {
        float4 v = *(const float4*)(p + (size_t)ks * MR * XLD + idx);
        s.x += v.x; s.y += v.y; s.z += v.z; s.w += v.w;
    }
    *(float4*)(xdb + (size_t)z * MR * XLD + idx) = s;
    int c = (int)(idx & (XLD - 1));
    if (c < 64) {
        size_t m = idx >> 7;
        ushort4 o;
        o.x = f2bf(s.x); o.y = f2bf(s.y); o.z = f2bf(s.z); o.w = f2bf(s.w);
        *(ushort4*)((unsigned short*)xdbt + (size_t)z * MR * 64 + m * 64 + c) = o;
    }
}

// ---------------- Depthwise conv (width 4) + SiLU, both dirs ----------------
__global__ __launch_bounds__(256) void conv_silu_k(
    const __hip_bfloat16* __restrict__ xz2,
    const float* __restrict__ fW, const float* __restrict__ fb,
    const float* __restrict__ bW, const float* __restrict__ bb_,
    __hip_bfloat16* __restrict__ xsb2)
{
    int dirv = blockIdx.y;
    int idx = blockIdx.x * 256 + threadIdx.x;   // over MR*DI
    int d = idx & (DI - 1);
    int m = idx >> 11;
    int t = m & (LL - 1);
    int bb = m >> 10;
    const float* w  = (dirv ? bW : fW) + d * 4;
    const __hip_bfloat16* xz = xz2 + (size_t)dirv * MR * 2 * DI;
    float acc = (dirv ? bb_ : fb)[d];
    if (dirv == 0) {
        #pragma unroll
        for (int k = 0; k < 4; ++k) {
            int tt = t - 3 + k;
            if (tt >= 0)
                acc = fmaf(w[k], bf2f(xz[(size_t)(bb * LL + tt) * (2 * DI) + d]), acc);
        }
    } else {
        #pragma unroll
        for (int k = 0; k < 4; ++k) {
            int tt = t + 3 - k;
            if (tt < LL)
                acc = fmaf(w[k], bf2f(xz[(size_t)(bb * LL + tt) * (2 * DI) + d]), acc);
        }
    }
    xsb2[(size_t)dirv * MR * DI + (size_t)m * DI + d] = __float2bfloat16(siluf(acc));
}

// ---------------- Chunked selective scan, both dirs ----------------
__global__ __launch_bounds__(256) void scan1_k(
    const __hip_bfloat16* __restrict__ dtf2, const __hip_bfloat16* __restrict__ xsb2,
    const float* __restrict__ xdb2,
    const float* __restrict__ fA, const float* __restrict__ bA,
    float* __restrict__ hend, float* __restrict__ aprod, int G, int Cn)
{
    int d  = blockIdx.x * 256 + threadIdx.x;
    int bb = blockIdx.y;
    int zz = blockIdx.z;
    int dirv = (zz >= G) ? 1 : 0;
    int g = zz - (dirv ? G : 0);
    const float* A_log = dirv ? bA : fA;
    const __hip_bfloat16* dtf = dtf2 + (size_t)dirv * MR * DI;
    const __hip_bfloat16* xs = xsb2 + (size_t)dirv * MR * DI;
    const float* xdb = xdb2 + (size_t)dirv * MR * XLD;
    size_t hoff = (size_t)dirv * G * (NB * DI * DST);

    float Ad[DST], h[DST], ap[DST];
    bool pw = true;
    #pragma unroll
    for (int s = 0; s < DST; ++s) {
        Ad[s] = -__expf(A_log[d * DST + s]);
        pw = pw && (fabsf(Ad[s] + (float)(s + 1)) < 1e-3f * (s + 1));
        h[s] = 0.f; ap[s] = 1.f;
    }
    int i0 = g * Cn;
    for (int i = 0; i < Cn; ++i) {
        int ii = i0 + i;
        int t = dirv ? (LL - 1 - ii) : ii;
        size_t m = (size_t)bb * LL + t;
        float dtv = bf2f(dtf[m * DI + d]);
        float xv  = bf2f(xs[m * DI + d]);
        const float* bc = xdb + m * XLD;
        float dtx = dtv * xv;
        float dAv[DST];
        if (pw) {
            float r = __expf(-dtv);
            float a = r;
            #pragma unroll
            for (int s = 0; s < DST; ++s) { dAv[s] = a; a *= r; }
        } else {
            #pragma unroll
            for (int s = 0; s < DST; ++s) dAv[s] = __expf(dtv * Ad[s]);
        }
        #pragma unroll
        for (int s = 0; s < DST; ++s) {
            h[s] = fmaf(h[s], dAv[s], dtx * bc[64 + s]);
            ap[s] *= dAv[s];
        }
    }
    size_t base = hoff + ((size_t)(g * NB + bb) * DI + d) * DST;
    #pragma unroll
    for (int s = 0; s < DST; s += 4) {
        *(float4*)(hend  + base + s) = make_float4(h[s], h[s+1], h[s+2], h[s+3]);
        *(float4*)(aprod + base + s) = make_float4(ap[s], ap[s+1], ap[s+2], ap[s+3]);
    }
}

__global__ __launch_bounds__(256) void scan2_k(
    float* __restrict__ hend, const float* __restrict__ aprod, int G)
{
    int dirv = blockIdx.y;
    int idx = blockIdx.x * 256 + threadIdx.x;   // over NB*DI*DST
    const int slab = NB * DI * DST;
    size_t hoff = (size_t)dirv * G * slab;
    float carry = 0.f;
    for (int g = 0; g < G; ++g) {
        size_t off = hoff + (size_t)g * slab + idx;
        float a = aprod[off];
        float e = hend[off];
        hend[off] = carry;
        carry = fmaf(a, carry, e);
    }
}

__global__ __launch_bounds__(256) void scan3_k(
    const __hip_bfloat16* __restrict__ dtf2, const __hip_bfloat16* __restrict__ xsb2,
    const float* __restrict__ xdb2, const __hip_bfloat16* __restrict__ xz2,
    const float* __restrict__ fA, const float* __restrict__ bA,
    const float* __restrict__ fD, const float* __restrict__ bD,
    const float* __restrict__ hin, __hip_bfloat16* __restrict__ ycat, int G, int Cn)
{
    int d  = blockIdx.x * 256 + threadIdx.x;
    int bb = blockIdx.y;
    int zz = blockIdx.z;
    int dirv = (zz >= G) ? 1 : 0;
    int g = zz - (dirv ? G : 0);
    const float* A_log = dirv ? bA : fA;
    const float* Dskip = dirv ? bD : fD;
    const __hip_bfloat16* dtf = dtf2 + (size_t)dirv * MR * DI;
    const __hip_bfloat16* xs = xsb2 + (size_t)dirv * MR * DI;
    const float* xdb = xdb2 + (size_t)dirv * MR * XLD;
    const __hip_bfloat16* xz = xz2 + (size_t)dirv * MR * 2 * DI;
    size_t hoff = (size_t)dirv * G * (NB * DI * DST);

    float Ad[DST], h[DST];
    bool pw = true;
    size_t base = hoff + ((size_t)(g * NB + bb) * DI + d) * DST;
    #pragma unroll
    for (int s = 0; s < DST; ++s) {
        Ad[s] = -__expf(A_log[d * DST + s]);
        pw = pw && (fabsf(Ad[s] + (float)(s + 1)) < 1e-3f * (s + 1));
        h[s] = hin[base + s];
    }
    float Dsk = Dskip[d];
    int i0 = g * Cn;
    for (int i = 0; i < Cn; ++i) {
        int ii = i0 + i;
        int t = dirv ? (LL - 1 - ii) : ii;
        size_t m = (size_t)bb * LL + t;
        float dtv = bf2f(dtf[m * DI + d]);
        float xv  = bf2f(xs[m * DI + d]);
        const float* bc = xdb + m * XLD;
        float dtx = dtv * xv;
        float dAv[DST];
        if (pw) {
            float r = __expf(-dtv);
            float a = r;
            #pragma unroll
            for (int s = 0; s < DST; ++s) { dAv[s] = a; a *= r; }
        } else {
            #pragma unroll
            for (int s = 0; s < DST; ++s) dAv[s] = __expf(dtv * Ad[s]);
        }
        float yv = 0.f;
        #pragma unroll
        for (int s = 0; s < DST; ++s) {
            h[s] = fmaf(h[s], dAv[s], dtx * bc[64 + s]);
            yv = fmaf(h[s], bc[80 + s], yv);
        }
        float zv = bf2f(xz[m * (2 * DI) + DI + d]);
        ycat[m * (2 * DI) + (size_t)dirv * DI + d] =
            __float2bfloat16((yv + xv * Dsk) * siluf(zv));
    }
}

// fallback monolithic scan (both dirs) if ws too small for chunk bufs
__global__ __launch_bounds__(256) void scan_mono_k(
    const __hip_bfloat16* __restrict__ dtf2, const __hip_bfloat16* __restrict__ xsb2,
    const float* __restrict__ xdb2, const __hip_bfloat16* __restrict__ xz2,
    const float* __restrict__ fA, const float* __restrict__ bA,
    const float* __restrict__ fD, const float* __restrict__ bD,
    __hip_bfloat16* __restrict__ ycat)
{
    int d  = blockIdx.x * 256 + threadIdx.x;
    int bb = blockIdx.y;
    int dirv = blockIdx.z;
    const float* A_log = dirv ? bA : fA;
    const float* Dskip = dirv ? bD : fD;
    const __hip_bfloat16* dtf = dtf2 + (size_t)dirv * MR * DI;
    const __hip_bfloat16* xs = xsb2 + (size_t)dirv * MR * DI;
    const float* xdb = xdb2 + (size_t)dirv * MR * XLD;
    const __hip_bfloat16* xz = xz2 + (size_t)dirv * MR * 2 * DI;
    float Ad[DST], h[DST];
    #pragma unroll
    for (int s = 0; s < DST; ++s) { Ad[s] = -__expf(A_log[d * DST + s]); h[s] = 0.f; }
    float Dsk = Dskip[d];
    for (int i = 0; i < LL; ++i) {
        int t = dirv ? (LL - 1 - i) : i;
        size_t m = (size_t)bb * LL + t;
        float dtv = bf2f(dtf[m * DI + d]);
        float xv  = bf2f(xs[m * DI + d]);
        const float* bc = xdb + m * XLD;
        float dtx = dtv * xv;
        float yv = 0.f;
        #pragma unroll
        for (int s = 0; s < DST; ++s) {
            float dA = __expf(dtv * Ad[s]);
            h[s] = fmaf(h[s], dA, dtx * bc[64 + s]);
            yv = fmaf(h[s], bc[80 + s], yv);
        }
        float zv = bf2f(xz[m * (2 * DI) + DI + d]);
        ycat[m * (2 * DI) + (size_t)dirv * DI + d] =
            __float2bfloat16((yv + xv * Dsk) * siluf(zv));
    }
}

// ---------------- final reduce: out = x + proj_b + sum_z part[z] ----------------
__global__ __launch_bounds__(256) void final_reduce_k(
    const float* __restrict__ part, const float* __restrict__ x,
    const float* __restrict__ proj_b, float* __restrict__ out)
{
    size_t idx = ((size_t)blockIdx.x * 256 + threadIdx.x) * 4;   // over MR*DM
    float4 s = make_float4(0.f, 0.f, 0.f, 0.f);
    #pragma unroll
    for (int z = 0; z < 4; ++z) {
        float4 v = *(const float4*)(part + (size_t)z * MR * DM + idx);
        s.x += v.x; s.y += v.y; s.z += v.z; s.w += v.w;
    }
    float4 xv = *(const float4*)(x + idx);
    float4 pb = *(const float4*)(proj_b + (idx & (DM - 1)));
    float4 o;
    o.x = xv.x + pb.x + s.x;
    o.y = xv.y + pb.y + s.y;
    o.z = xv.z + pb.z + s.z;
    o.w = xv.w + pb.w + s.w;
    *(float4*)(out + idx) = o;
}

// ---------------- Launch ----------------
extern "C" void kernel_launch(void* const* d_in, const int* in_sizes, int n_in,
                              void* d_out, int out_size, void* d_ws, size_t ws_size,
                              hipStream_t stream)
{
    const float* x      = (const float*)d_in[0];
    const float* ln_w   = (const float*)d_in[1];
    const float* ln_b   = (const float*)d_in[2];
    const float* f_inW    = (const float*)d_in[3];
    const float* f_convW  = (const float*)d_in[4];
    const float* f_convb  = (const float*)d_in[5];
    const float* f_xprojW = (const float*)d_in[6];
    const float* f_dtW    = (const float*)d_in[7];
    const float* f_dtb    = (const float*)d_in[8];
    const float* f_A_log  = (const float*)d_in[9];
    const float* f_Dskip  = (const float*)d_in[10];
    const float* f_outW   = (const float*)d_in[11];
    const float* b_inW    = (const float*)d_in[12];
    const float* b_convW  = (const float*)d_in[13];
    const float* b_convb  = (const float*)d_in[14];
    const float* b_xprojW = (const float*)d_in[15];
    const float* b_dtW    = (const float*)d_in[16];
    const float* b_dtb    = (const float*)d_in[17];
    const float* b_A_log  = (const float*)d_in[18];
    const float* b_Dskip  = (const float*)d_in[19];
    const float* b_outW   = (const float*)d_in[20];
    const float* proj_W = (const float*)d_in[21];
    const float* proj_b = (const float*)d_in[22];

    float* ws = (float*)d_ws;
    size_t o = 0;
    // xz2 region (8,388,608 floats): xz2 bf16 [2][MR][2DI], then final split-K
    // fp32 partials [4][MR][DM] (xz2 dead after scan3).
    __hip_bfloat16* xz2  = (__hip_bfloat16*)(ws + o);
    float* fpart = ws + o;
    o += (size_t)2 * MR * 2 * DI / 2;
    __hip_bfloat16* xsb2 = (__hip_bfloat16*)(ws + o); o += (size_t)2 * MR * DI / 2;
    // ycat region: x-proj split-K fp32 partials first, then ycat bf16 [MR][2DI].
    __hip_bfloat16* ycat = (__hip_bfloat16*)(ws + o);
    float* xpart = ws + o;
    o += (size_t)MR * 2 * DI / 2;
    float* xdb2 = ws + o; o += (size_t)2 * MR * XLD;
    __hip_bfloat16* xdbt = (__hip_bfloat16*)(ws + o); o += (size_t)2 * MR * 64 / 2;
    __hip_bfloat16* dtfb = (__hip_bfloat16*)(ws + o); o += (size_t)2 * MR * DI / 2;
    __hip_bfloat16* nb = (__hip_bfloat16*)(ws + o); o += (size_t)MR * DM / 2;
    __hip_bfloat16* warena = (__hip_bfloat16*)(ws + o); o += 15466496 / 2;
    float* hbuf = ws + o;
    size_t base_floats = o;

    __hip_bfloat16* wbi  = warena;               // [2][2DI][DM]    8,388,608
    __hip_bfloat16* pwb  = warena +  8388608;    // [DM][2DM]       2,097,152
    __hip_bfloat16* wdt  = warena + 10485760;    // [2][DI][64]       262,144
    __hip_bfloat16* wpb2 = warena + 10747904;    // [2][128][DI]      524,288
    __hip_bfloat16* wcat = warena + 11272192;    // [DM][2DI]       4,194,304

    const size_t slab = (size_t)NB * DI * DST;   // 65536
    int G = 32;
    while (G > 4 && (base_floats + 4ull * G * slab) * 4 > ws_size) G >>= 1;
    int useChunks = ((base_floats + 4ull * G * slab) * 4 <= ws_size);
    float* hend  = hbuf;
    float* aprod = hbuf + 2ull * G * slab;
    int Cn = useChunks ? LL / G : LL;

    // wot [2][DI][DM] bf16 (4,194,304 elems = 2,097,152 floats): lives in the
    // scan hbuf region when chunked (hbuf = 4*G*slab >= 8.4M floats at G>=8;
    // Wcat finishes inside the merged dispatch, before scan1 overwrites it).
    // Non-chunked fallback: wot aliases xz2 and Wcat runs as its own dispatch
    // before in-proj (R9 ordering).
    int wotInHbuf = useChunks && (4ull * G * slab >= 2097152ull);
    __hip_bfloat16* wot = wotInHbuf ? (__hip_bfloat16*)hbuf : xz2;

    // 1: mega-prep (weight cvts + transpose + layernorm)
    prep_k<<<13696, 256, 0, stream>>>(
        f_inW, b_inW, proj_W, f_dtW, b_dtW, warena,
        f_xprojW, b_xprojW, wpb2,
        f_outW, b_outW, wot,
        x, ln_w, ln_b, nb);

    // 2: in-proj (z=0,1) + Wcat (z=2,3) in one dispatch (or split if fallback)
    if (wotInHbuf) {
        inproj_wcat_k<<<dim3(32, 16, 4), 256, 0, stream>>>(
            nb, wbi, xz2, pwb, wot, wcat);
    } else {
        gemm_gl<1><<<dim3(DI / 128, DM / 128, 2), 256, 0, stream>>>(
            pwb, 2 * DM, (size_t)DM, wot, DM, (size_t)DI * DM,
            wcat, 2 * DI, (size_t)DI, DM, nullptr, nullptr);
        inproj_wcat_k<<<dim3(32, 16, 2), 256, 0, stream>>>(
            nb, wbi, xz2, pwb, wot, wcat);
    }

    // 3: conv + silu both dirs -> xsb2
    conv_silu_k<<<dim3((MR * DI) / 256, 2), 256, 0, stream>>>(
        xz2, f_convW, f_convb, b_convW, b_convb, xsb2);

    // 4-5: x-proj split-K + reduce
    xproj_part_k<<<dim3(KS, MR / 128, 2), 256, 0, stream>>>(xsb2, wpb2, xpart);
    xproj_reduce_k<<<dim3((MR * XLD) / 1024, 2), 256, 0, stream>>>(xpart, xdb2, xdbt);

    // 6: dt-proj both dirs: dtfb = softplus(xdbt @ dtW^T + dtb) (bf16)
    gemm_gl<3><<<dim3(DI / 128, MR / 128, 2), 256, 0, stream>>>(
        xdbt, 64, (size_t)MR * 64, wdt, 64, (size_t)DI * 64,
        dtfb, DI, (size_t)MR * DI, 64, f_dtb, b_dtb);

    // 7-9: selective scan both dirs -> ycat [MR][2*DI]
    if (useChunks) {
        scan1_k<<<dim3(DI / 256, NB, 2 * G), 256, 0, stream>>>(
            dtfb, xsb2, xdb2, f_A_log, b_A_log, hend, aprod, G, Cn);
        scan2_k<<<dim3((NB * DI * DST) / 256, 2), 256, 0, stream>>>(hend, aprod, G);
        scan3_k<<<dim3(DI / 256, NB, 2 * G), 256, 0, stream>>>(
            dtfb, xsb2, xdb2, xz2, f_A_log, b_A_log, f_Dskip, b_Dskip,
            hend, ycat, G, Cn);
    } else {
        scan_mono_k<<<dim3(DI / 256, NB, 2), 256, 0, stream>>>(
            dtfb, xsb2, xdb2, xz2, f_A_log, b_A_log, f_Dskip, b_Dskip, ycat);
    }

    // 10: final split-K GEMM -> fp32 partials (overwrites xz2 region)
    gemm_gl<0><<<dim3(DM / 128, MR / 128, 4), 256, 0, stream>>>(
        ycat, 2 * DI, 1024, wcat, 2 * DI, 1024,
        fpart, DM, (size_t)MR * DM, 1024, nullptr, nullptr);

    // 11: out = x + proj_b + sum_z fpart
    final_reduce_k<<<(MR * DM) / 1024, 256, 0, stream>>>(
        fpart, x, proj_b, (float*)d_out);
}